// Round 9
// baseline (858.431 us; speedup 1.0000x reference)
//
#include <hip/hip_runtime.h>
#include <hip/hip_bf16.h>

typedef unsigned short u16;
typedef signed char i8;
typedef __attribute__((ext_vector_type(4))) float f32x4;
typedef __attribute__((ext_vector_type(4))) int i32x4;
typedef __attribute__((ext_vector_type(8))) short bf16x8;
typedef __attribute__((ext_vector_type(2))) unsigned int u32x2;

#define HID 256
#define NG 1024
#define TSTEPS 512
#define BATCH 256
#define CH 16          // steps per chunk (persistent mode: small chunk = small lag)
#define NCH 32         // chunks (CH*NCH = 512)
#define BB 4           // batch rows per rec block (1 cell/lane via A-row duplication)
#define HSTR 288       // h_lds row stride bytes
#define LOG2E 1.4426950408889634f
#define PRE_TSTR 262144   // per-t' element stride in pre: 64 btiles * 4 j * 1024 (u*4+kb)
#define H0C_TSTR 65536    // per-t element stride in h0c frag layout [kk][bt][kgrp][col][e]
#define PRE_ELE  4194304  // CH*BATCH*NG      (8 MB per parity)
#define H0C_ELE  1048576  // CH*BATCH*HID     (2 MB per parity)

// persistent roles: rec [0,128), gemm0 [128,160), gemm1 [160,224)
#define NBLK 224
// dynamic LDS per block: 84KB -> 2 blocks/CU impossible (168KB > 160KB) ->
// all 224 blocks co-resident on distinct CUs: pipeline deadlock-free by capacity.
#define DYN_LDS 86016

#define MFMA_BF16(a, b, c) __builtin_amdgcn_mfma_f32_16x16x32_bf16((a), (b), (c), 0, 0, 0)
#define MFMA_I8(a, b, c)   __builtin_amdgcn_mfma_i32_16x16x64_i8((a), (b), (c), 0, 0, 0)

__device__ __forceinline__ float rcpf_(float x) {
#if __has_builtin(__builtin_amdgcn_rcpf)
    return __builtin_amdgcn_rcpf(x);
#else
    return 1.f / x;
#endif
}
__device__ __forceinline__ float exp2_(float x) {
#if __has_builtin(__builtin_amdgcn_exp2f)
    return __builtin_amdgcn_exp2f(x);
#else
    return exp2f(x);
#endif
}
__device__ __forceinline__ float sigm2(float y) { return rcpf_(1.f + exp2_(-y)); }
__device__ __forceinline__ float tanh2(float y2) { return fmaf(-2.f, rcpf_(exp2_(y2) + 1.f), 1.f); }
__device__ __forceinline__ u16 f2bf(float v){ __hip_bfloat16 h=__float2bfloat16(v); return __builtin_bit_cast(u16,h); }
__device__ __forceinline__ float bf2f(u16 u){ unsigned x=((unsigned)u)<<16; return __builtin_bit_cast(float,x); }

// ---------------------------------------------------------------------------
// prep_a: per-gate-row i8 scales for Whh0/Whh1; log2e folded into dequant
// scales and biases. (unchanged)
// ---------------------------------------------------------------------------
__global__ void prep_a(const float* __restrict__ Whh0, const float* __restrict__ Whh1,
                       const float* __restrict__ bih0, const float* __restrict__ bhh0,
                       const float* __restrict__ bih1, const float* __restrict__ bhh1,
                       float* __restrict__ qs0, float* __restrict__ dq0s,
                       float* __restrict__ qs1, float* __restrict__ dq1s,
                       float* __restrict__ b0s, float* __restrict__ b1s) {
    int r = blockIdx.x * blockDim.x + threadIdx.x;
    if (r >= NG) return;
    float m0 = 1e-20f, m1 = 1e-20f;
    for (int k = 0; k < HID; k++) {
        m0 = fmaxf(m0, fabsf(Whh0[r * HID + k]));
        m1 = fmaxf(m1, fabsf(Whh1[r * HID + k]));
    }
    qs0[r] = 127.f / m0;   dq0s[r] = m0 / 16129.f * LOG2E;
    qs1[r] = 127.f / m1;   dq1s[r] = m1 / 16129.f * LOG2E;
    b0s[r] = (bih0[r] + bhh0[r]) * LOG2E;
    b1s[r] = (bih1[r] + bhh1[r]) * LOG2E;
}

// ---------------------------------------------------------------------------
// prep_b: i8 frag packs; bf16 Wih1/Wih0 frags (x LOG2E); x padded; zero flags.
// (flags re-zeroed every kernel_launch call -> graph replays start clean)
// ---------------------------------------------------------------------------
__global__ void prep_b(const float* __restrict__ x,
    const float* __restrict__ Wih0, const float* __restrict__ Whh0,
    const float* __restrict__ Wih1, const float* __restrict__ Whh1,
    const float* __restrict__ qs0, const float* __restrict__ qs1,
    i8* __restrict__ wi80, i8* __restrict__ wi81,
    u16* __restrict__ wih1f, u16* __restrict__ wih0f,
    u16* __restrict__ xpad, int* __restrict__ flags)
{
    const int stride = gridDim.x * blockDim.x;
    const int tid = blockIdx.x * blockDim.x + threadIdx.x;
    for (int i = tid; i < NG * HID; i += stride) {   // i8 packs (recurrent)
        int e = i & 15, l = (i >> 4) & 63, kc = (i >> 10) & 3, gt = i >> 12;
        int row = 16 * gt + (l & 15);
        int k = kc * 64 + (l >> 4) * 16 + e;
        float q0 = __builtin_rintf(Whh0[row * HID + k] * qs0[row]);
        float q1 = __builtin_rintf(Whh1[row * HID + k] * qs1[row]);
        wi80[i] = (i8)fminf(fmaxf(q0, -127.f), 127.f);
        wi81[i] = (i8)fminf(fmaxf(q1, -127.f), 127.f);
    }
    for (int i = tid; i < NG * HID; i += stride) {   // Wih1 bf16 frags, scaled
        int gt = i >> 12, kk = (i >> 9) & 7, l = (i >> 3) & 63, e = i & 7;
        wih1f[i] = f2bf(Wih1[(16 * gt + (l & 15)) * HID + kk * 32 + (l >> 4) * 8 + e] * LOG2E);
    }
    for (int i = tid; i < 32768; i += stride) {      // Wih0 bf16 frags, scaled
        int gt = i >> 9, l = (i >> 3) & 63, e = i & 7;
        int k = (l >> 4) * 8 + e;
        wih0f[i] = (k < 5) ? f2bf(Wih0[(16 * gt + (l & 15)) * 5 + k] * LOG2E) : (u16)0;
    }
    for (int i = tid; i < TSTEPS * BATCH * 8; i += stride) {  // x padded to 8, token-major
        int tok = i >> 3, k = i & 7, t = tok >> 8, b = tok & 255;
        xpad[i] = (k < 5) ? f2bf(x[((size_t)b * TSTEPS + t) * 5 + k]) : (u16)0;
    }
    for (int i = tid; i < 256; i += stride) flags[i] = 0;
}

// ---------------------------------------------------------------------------
// persistent_fused: the whole pipeline in ONE launch. Roles on disjoint CUs
// (co-residency guaranteed by 84KB LDS/block), chunk-granularity flag sync:
//   rec0(c):  wait g0c[c]==32, c>=2: g1c[c-2]==64 (h0c parity WAR) -> r0c[c]++
//   gemm1(c): wait r0c[c]==64, c>=2: r1c[c-2]==64 (pre1 parity WAR) -> g1c[c]++
//   rec1(c):  wait g1c[c]==64                                      -> r1c[c]++
//   gemm0(c): c>=2: wait r0c[c-2]==64 (pre0 parity WAR)            -> g0c[c]++
// Polling: RELAXED agent loads (no cache inv per poll); one ACQUIRE on
// success (invalidate reader L2 once/chunk); publish: __syncthreads (drains
// vmcnt for all waves -> stores in XCD L2) then RELEASE fetch_add (wbl2 ->
// L3 = coherent point). Weights/state stay in VGPR/LDS across all chunks:
// no per-stage prologue, no hs/cs global round-trip. Math/order/layouts
// identical to R8 -> bit-identical output.
// ---------------------------------------------------------------------------
__global__ __launch_bounds__(1024) __attribute__((amdgpu_waves_per_eu(4, 4)))
void persistent_fused(
    const u16* __restrict__ xpad8, const u16* __restrict__ wih0f, const float* __restrict__ b0s,
    const u16* __restrict__ wih1f, const float* __restrict__ b1s,
    u16* __restrict__ pre0, u16* __restrict__ h0c, u16* __restrict__ pre1,
    const i8* __restrict__ wi80, const i8* __restrict__ wi81,
    const float* __restrict__ dq0s, const float* __restrict__ dq1s,
    i8* __restrict__ hs1, int* __restrict__ flags)
{
    extern __shared__ __align__(16) char smem[];
    const int bid = blockIdx.x;
    const int tid = threadIdx.x, lane = tid & 63;
    const int col = lane & 15, kgrp = lane >> 4;

    int* g0c = flags;          // gemm0 done count per chunk (target 32)
    int* r0c = flags + 64;     // rec0  (target 64)
    int* g1c = flags + 128;    // gemm1 (target 64)
    int* r1c = flags + 192;    // rec1  (target 64)

#define SPIN_WAIT(P, TGT) do {                                                      \
        while (__hip_atomic_load((P), __ATOMIC_RELAXED, __HIP_MEMORY_SCOPE_AGENT)   \
               < (TGT))                                                             \
            __builtin_amdgcn_s_sleep(2);                                            \
        (void)__hip_atomic_load((P), __ATOMIC_ACQUIRE, __HIP_MEMORY_SCOPE_AGENT);   \
    } while (0)

    if (bid < 128) {
        // ---------------- recurrent role (BB=4, R8-identical math) ----------------
        const int layer = bid >> 6;
        const int btile = bid & 63;
        i8 (*h_lds)[BB * HSTR] = (i8 (*)[BB * HSTR])smem;
        const i8*  wi8   = layer ? wi81 : wi80;
        const float* dq  = layer ? dq1s : dq0s;
        const int w = tid >> 6;
        const int b0 = btile * BB;
        const int u = w * 16 + col;          // h-unit this lane owns

        float sc[4];
        i32x4 wv[4][4];                      // 64 VGPRs resident weights (whole run)
#pragma unroll
        for (int j = 0; j < 4; j++) {
            const int gt = 16 * j + w;
            sc[j] = dq[gt * 16 + col];
#pragma unroll
            for (int kc = 0; kc < 4; kc++)
                wv[j][kc] = ((const i32x4*)wi8)[(gt * 4 + kc) * 64 + lane];
        }
        if (tid < 64 * BB) {                 // h_0 = 0
            const int rrow = tid >> 6, cc = (tid & 63) * 4;
            *(int*)&h_lds[0][rrow * HSTR + cc] = 0;
        }
        float c_reg = 0.f;                   // c_0 = 0; persists in register

        const u16* pb0 = (layer ? pre1 : pre0) + ((size_t)btile << 12) + (u << 2) + kgrp;
        const size_t h0base = ((((size_t)(w >> 1) * 16 + (btile >> 2)) * 4
                               + ((w & 1) * 2 + (col >> 3))) * 16
                              + ((btile & 3) * 4 + kgrp)) * 8 + (col & 7);
        __syncthreads();

#pragma unroll 1
        for (int c = 0; c < NCH; ++c) {
            if (tid == 0) {
                if (layer == 0) {
                    SPIN_WAIT(&g0c[c], 32);
                    if (c >= 2) SPIN_WAIT(&g1c[c - 2], 64);
                } else {
                    SPIN_WAIT(&g1c[c], 64);
                }
            }
            __syncthreads();
            const u16* pb = pb0 + (size_t)(c & 1) * PRE_ELE;
            u16* h0wc = h0c + (size_t)(c & 1) * H0C_ELE;
            u16 pvA[4], pvB[4];
#pragma unroll
            for (int j = 0; j < 4; j++) pvA[j] = pb[j << 10];

#define REC_STEP(T, CUR, PVC, PVN) do {                                             \
        _Pragma("unroll")                                                           \
        for (int j = 0; j < 4; j++)                                                 \
            asm volatile("" : "+v"(wv[j][0]), "+v"(wv[j][1]),                       \
                              "+v"(wv[j][2]), "+v"(wv[j][3]));                      \
        i32x4 acc[4];                                                               \
        _Pragma("unroll")                                                           \
        for (int j = 0; j < 4; j++) acc[j] = (i32x4){0, 0, 0, 0};                   \
        _Pragma("unroll")                                                           \
        for (int kc = 0; kc < 4; kc++) {                                            \
            i32x4 a_ = *(const i32x4*)&h_lds[CUR][(col >> 2) * HSTR + kc * 64 + kgrp * 16]; \
            _Pragma("unroll")                                                       \
            for (int j = 0; j < 4; j++) acc[j] = MFMA_I8(a_, wv[j][kc], acc[j]);    \
        }                                                                           \
        const int tn_ = ((T) + 1 < CH) ? (T) + 1 : (T);                             \
        _Pragma("unroll")                                                           \
        for (int j = 0; j < 4; j++) PVN[j] = pb[(size_t)tn_ * PRE_TSTR + (j << 10)];\
        const float yi = fmaf((float)acc[0][0], sc[0], bf2f(PVC[0]));               \
        const float yf = fmaf((float)acc[1][0], sc[1], bf2f(PVC[1]));               \
        const float yg = fmaf((float)acc[2][0], sc[2], bf2f(PVC[2]));               \
        const float yo = fmaf((float)acc[3][0], sc[3], bf2f(PVC[3]));               \
        const float iv = sigm2(yi), fv = sigm2(yf), ov = sigm2(yo);                 \
        const float gv = tanh2(yg + yg);                                            \
        const float cn = fmaf(fv, c_reg, iv * gv);                                  \
        c_reg = cn;                                                                 \
        const float hv = ov * tanh2(cn * (2.f * LOG2E));                            \
        h_lds[(CUR) ^ 1][kgrp * HSTR + u] = (i8)__float2int_rn(hv * 127.f);         \
        if (layer == 0)                                                             \
            h0wc[h0base + (size_t)(T) * H0C_TSTR] = f2bf(hv);                       \
        asm volatile("s_waitcnt lgkmcnt(0)" ::: "memory");                          \
        __builtin_amdgcn_s_barrier();                                               \
        __builtin_amdgcn_sched_barrier(0);                                          \
    } while (0)

#pragma unroll 1
            for (int t2 = 0; t2 < CH; t2 += 2) {
                REC_STEP(t2,     0, pvA, pvB);
                REC_STEP(t2 + 1, 1, pvB, pvA);
            }
#undef REC_STEP

            __syncthreads();   // drain h0c stores (+pre reads) into this XCD's L2
            if (tid == 0)
                __hip_atomic_fetch_add(layer ? &r1c[c] : &r0c[c], 1,
                                       __ATOMIC_RELEASE, __HIP_MEMORY_SCOPE_AGENT);
        }
        if (layer == 1 && tid < 64 * BB) {   // final h for the head
            const int rrow = tid >> 6, cc = (tid & 63) * 4;
            *(int*)&hs1[(b0 + rrow) * HID + cc] = *(const int*)&h_lds[0][rrow * HSTR + cc];
        }
        return;
    } else if (bid < 160) {
        // ---------------- gemm0 role: pre0(c) = log2e*(Wih0 x + b0) ----------------
        const int g = bid - 128;             // 0..31
        const int tp = g >> 1, bh = g & 1;   // t' 0..15, batch half
        const int w = tid >> 6;              // wave 0..15
        const int j = w >> 2;                // pre j-chunk, constant per wave
        float bias[4];
        bf16x8 wv4[4];
#pragma unroll
        for (int tm = 0; tm < 4; tm++) {
            const int tile = w * 4 + tm;     // 16-gate tile 0..63
            bias[tm] = b0s[tile * 16 + col];
            wv4[tm] = *(const bf16x8*)&wih0f[((size_t)tile * 64 + lane) * 8];
        }
#pragma unroll 1
        for (int c = 0; c < NCH; ++c) {
            if (tid == 0 && c >= 2) SPIN_WAIT(&r0c[c - 2], 64);
            __syncthreads();
            const u16* Ab = xpad8 + ((size_t)c * CH + tp) * BATCH * 8;
            u16* p0wc = pre0 + (size_t)(c & 1) * PRE_ELE;
#pragma unroll 1
            for (int bt = 0; bt < 8; bt++) {
                const int btg = bh * 8 + bt;
                bf16x8 af = {0, 0, 0, 0, 0, 0, 0, 0};
                if (kgrp == 0) af = *(const bf16x8*)&Ab[(btg * 16 + col) * 8];
                f32x4 acc[4];
#pragma unroll
                for (int tm = 0; tm < 4; tm++) acc[tm] = (f32x4){bias[tm], bias[tm], bias[tm], bias[tm]};
#pragma unroll
                for (int tm = 0; tm < 4; tm++) acc[tm] = MFMA_BF16(af, wv4[tm], acc[tm]);
#pragma unroll
                for (int tm = 0; tm < 4; tm++) {
                    const int ul = ((w & 3) * 4 + tm) * 16 + col;
                    const size_t off = ((((size_t)tp * 64 + btg * 4 + kgrp) * 4 + j) << 10) + (ul << 2);
                    u32x2 pk;
                    pk.x = (unsigned)f2bf(acc[tm][0]) | ((unsigned)f2bf(acc[tm][1]) << 16);
                    pk.y = (unsigned)f2bf(acc[tm][2]) | ((unsigned)f2bf(acc[tm][3]) << 16);
                    *(u32x2*)&p0wc[off] = pk;
                }
            }
            __syncthreads();   // drain pre0 stores into L2
            if (tid == 0)
                __hip_atomic_fetch_add(&g0c[c], 1, __ATOMIC_RELEASE, __HIP_MEMORY_SCOPE_AGENT);
        }
        return;
    } else {
        // ---------------- gemm1 role: pre1(c) = log2e*(Wih1 h0 + b1), LDS-staged A ----------------
        const int g = bid - 160;             // 0..63
        const int tp = g >> 2, j = g & 3;    // t' 0..15, j-chunk 0..3
        const int w = tid >> 6;              // wave = 16-gate tile within j
        const int gt = j * 16 + w;
        const float bias = b1s[gt * 16 + col];
        bf16x8 wv8[8];                       // 32 VGPRs resident weights
#pragma unroll
        for (int kk = 0; kk < 8; kk++)
            wv8[kk] = *(const bf16x8*)&wih1f[((size_t)(gt * 8 + kk) * 64 + lane) * 8];
        u16* As = (u16*)smem;                // [2][8][512] u16 double buffer
        const int kks = tid >> 7;            // staging slice: kk
        const int e4 = (tid & 127) * 4;      // 4 elements (8B) per thread
#pragma unroll 1
        for (int c = 0; c < NCH; ++c) {
            if (tid == 0) {
                SPIN_WAIT(&r0c[c], 64);
                if (c >= 2) SPIN_WAIT(&r1c[c - 2], 64);
            }
            __syncthreads();
            const u16* Asrc = h0c + (size_t)(c & 1) * H0C_ELE + (size_t)tp * H0C_TSTR;
            u16* p1wc = pre1 + (size_t)(c & 1) * PRE_ELE;
            {   // prologue: stage bt=0 into buf0
                u32x2 st = *(const u32x2*)&Asrc[((size_t)kks * 16 + 0) * 512 + e4];
                *(u32x2*)&As[kks * 512 + e4] = st;
            }
            __syncthreads();
#pragma unroll 1
            for (int bt = 0; bt < 16; bt++) {
                const int cur = bt & 1, nxt = cur ^ 1;
                u32x2 nx;
                if (bt + 1 < 16)
                    nx = *(const u32x2*)&Asrc[((size_t)kks * 16 + bt + 1) * 512 + e4];
                bf16x8 a8[8];
#pragma unroll
                for (int kk = 0; kk < 8; kk++)
                    a8[kk] = *(const bf16x8*)&As[cur * 4096 + kk * 512 + lane * 8];
                f32x4 acc = (f32x4){bias, bias, bias, bias};
#pragma unroll
                for (int kk = 0; kk < 8; kk++)
                    acc = MFMA_BF16(a8[kk], wv8[kk], acc);
                const int ul = w * 16 + col;
                const size_t off = ((((size_t)tp * 64 + bt * 4 + kgrp) * 4 + j) << 10) + (ul << 2);
                u32x2 pk;
                pk.x = (unsigned)f2bf(acc[0]) | ((unsigned)f2bf(acc[1]) << 16);
                pk.y = (unsigned)f2bf(acc[2]) | ((unsigned)f2bf(acc[3]) << 16);
                *(u32x2*)&p1wc[off] = pk;
                if (bt + 1 < 16)
                    *(u32x2*)&As[nxt * 4096 + kks * 512 + e4] = nx;
                __syncthreads();
            }
            __syncthreads();   // drain pre1 stores (and h0c reads) into L2
            if (tid == 0)
                __hip_atomic_fetch_add(&g1c[c], 1, __ATOMIC_RELEASE, __HIP_MEMORY_SCOPE_AGENT);
        }
        return;
    }
#undef SPIN_WAIT
}

// ---------------------------------------------------------------------------
// head: y = sigmoid(relu(h_last) @ Wh^T + bh)
// ---------------------------------------------------------------------------
__global__ void head_kernel(const i8* __restrict__ hs1,
                            const float* __restrict__ Wh, const float* __restrict__ bh,
                            float* __restrict__ y) {
    int b = blockIdx.x;
    int l = threadIdx.x;
    const float inv127 = 1.f / 127.f;
    float hr[4];
#pragma unroll
    for (int i = 0; i < 4; ++i) hr[i] = fmaxf((float)hs1[b * HID + l + 64 * i] * inv127, 0.f);
    for (int o = 0; o < 3; ++o) {
        float s = 0.f;
#pragma unroll
        for (int i = 0; i < 4; ++i) s += hr[i] * Wh[o * HID + l + 64 * i];
        for (int off = 32; off > 0; off >>= 1) s += __shfl_down(s, off, 64);
        if (l == 0) y[b * 3 + o] = 1.f / (1.f + exp2_(-(s + bh[o]) * LOG2E));
    }
}

extern "C" void kernel_launch(void* const* d_in, const int* in_sizes, int n_in,
                              void* d_out, int out_size, void* d_ws, size_t ws_size,
                              hipStream_t stream) {
    const float* x    = (const float*)d_in[0];
    const float* Wih0 = (const float*)d_in[1];
    const float* Whh0 = (const float*)d_in[2];
    const float* bih0 = (const float*)d_in[3];
    const float* bhh0 = (const float*)d_in[4];
    const float* Wih1 = (const float*)d_in[5];
    const float* Whh1 = (const float*)d_in[6];
    const float* bih1 = (const float*)d_in[7];
    const float* bhh1 = (const float*)d_in[8];
    const float* Wh   = (const float*)d_in[9];
    const float* bh   = (const float*)d_in[10];

    char* ws = (char*)d_ws;
    i8*    wi80  = (i8*)(ws);                            // 256 KB
    i8*    wi81  = (i8*)(ws + ((size_t)256 << 10));      // 256 KB
    u16*   wih1f = (u16*)(ws + ((size_t)512 << 10));     // 512 KB
    u16*   wih0f = (u16*)(ws + ((size_t)1024 << 10));    // 64 KB
    float* qs0   = (float*)(ws + ((size_t)1088 << 10));
    float* dq0s  = (float*)(ws + ((size_t)1092 << 10));
    float* qs1   = (float*)(ws + ((size_t)1096 << 10));
    float* dq1s  = (float*)(ws + ((size_t)1100 << 10));
    float* b0s   = (float*)(ws + ((size_t)1104 << 10));
    float* b1s   = (float*)(ws + ((size_t)1108 << 10));
    i8*    hs1   = (i8*)(ws + ((size_t)1176 << 10));     // 64 KB
    int*   flags = (int*)(ws + ((size_t)1440 << 10));    // 1 KB (256 ints)
    u16*   xpad  = (u16*)(ws + ((size_t)1752 << 10));    // 2 MB  [tok][8] bf16
    u16*   h0c   = (u16*)(ws + ((size_t)3800 << 10));    // 2 x 2 MB (chunk parity)
    u16*   pre0  = (u16*)(ws + ((size_t)7896 << 10));    // 2 x 8 MB (chunk parity)
    u16*   pre1  = (u16*)(ws + ((size_t)24280 << 10));   // 2 x 8 MB -> total ~40 MB

    prep_a<<<4, 256, 0, stream>>>(Whh0, Whh1, bih0, bhh0, bih1, bhh1,
                                  qs0, dq0s, qs1, dq1s, b0s, b1s);
    prep_b<<<1024, 256, 0, stream>>>(x, Wih0, Whh0, Wih1, Whh1, qs0, qs1,
                                     wi80, wi81, wih1f, wih0f, xpad, flags);
    persistent_fused<<<NBLK, 1024, DYN_LDS, stream>>>(
        xpad, wih0f, b0s, wih1f, b1s, pre0, h0c, pre1,
        wi80, wi81, dq0s, dq1s, hs1, flags);
    head_kernel<<<BATCH, 64, 0, stream>>>(hs1, Wh, bh, (float*)d_out);
}

// Round 10
// 773.717 us; speedup vs baseline: 1.1095x; 1.1095x over previous
//
#include <hip/hip_runtime.h>
#include <hip/hip_bf16.h>

typedef unsigned short u16;
typedef signed char i8;
typedef __attribute__((ext_vector_type(4))) float f32x4;
typedef __attribute__((ext_vector_type(4))) int i32x4;
typedef __attribute__((ext_vector_type(8))) short bf16x8;
typedef __attribute__((ext_vector_type(2))) unsigned int u32x2;

#define HID 256
#define NG 1024
#define TSTEPS 512
#define BATCH 256
#define CH 32          // steps per chunk (R8-proven)
#define NCH 16         // chunks (CH*NCH = 512)
#define BB 4           // batch rows per rec block (1 cell/lane via A-row duplication)
#define HSTR 288       // h_lds row stride bytes
#define LOG2E 1.4426950408889634f
#define PRE_TSTR 262144   // per-t' element stride in pre1: 64 btiles * 4 j * 1024 (u*4+kb)
#define H0C_TSTR 65536    // per-t element stride in h0c frag layout [kk][bt][kgrp][col][e]

// block roles: rec [0,128), gemm1 [128,192).  gemm0 is GONE (R9 post-mortem:
// IN_DIM=5 -> 20 fmaf/lane folded into rec0's cell, off the MFMA critical path)
#define GB1 128
#define NBLK 192

#define MFMA_BF16(a, b, c) __builtin_amdgcn_mfma_f32_16x16x32_bf16((a), (b), (c), 0, 0, 0)
#define MFMA_I8(a, b, c)   __builtin_amdgcn_mfma_i32_16x16x64_i8((a), (b), (c), 0, 0, 0)

__device__ __forceinline__ float rcpf_(float x) {
#if __has_builtin(__builtin_amdgcn_rcpf)
    return __builtin_amdgcn_rcpf(x);
#else
    return 1.f / x;
#endif
}
__device__ __forceinline__ float exp2_(float x) {
#if __has_builtin(__builtin_amdgcn_exp2f)
    return __builtin_amdgcn_exp2f(x);
#else
    return exp2f(x);
#endif
}
__device__ __forceinline__ float sigm2(float y) { return rcpf_(1.f + exp2_(-y)); }
__device__ __forceinline__ float tanh2(float y2) { return fmaf(-2.f, rcpf_(exp2_(y2) + 1.f), 1.f); }
__device__ __forceinline__ u16 f2bf(float v){ __hip_bfloat16 h=__float2bfloat16(v); return __builtin_bit_cast(u16,h); }
__device__ __forceinline__ float bf2f(u16 u){ unsigned x=((unsigned)u)<<16; return __builtin_bit_cast(float,x); }

// ---------------------------------------------------------------------------
// prep_a: per-gate-row i8 scales for Whh0/Whh1; log2e folded into dequant
// scales and biases. (unchanged)
// ---------------------------------------------------------------------------
__global__ void prep_a(const float* __restrict__ Whh0, const float* __restrict__ Whh1,
                       const float* __restrict__ bih0, const float* __restrict__ bhh0,
                       const float* __restrict__ bih1, const float* __restrict__ bhh1,
                       float* __restrict__ qs0, float* __restrict__ dq0s,
                       float* __restrict__ qs1, float* __restrict__ dq1s,
                       float* __restrict__ b0s, float* __restrict__ b1s) {
    int r = blockIdx.x * blockDim.x + threadIdx.x;
    if (r >= NG) return;
    float m0 = 1e-20f, m1 = 1e-20f;
    for (int k = 0; k < HID; k++) {
        m0 = fmaxf(m0, fabsf(Whh0[r * HID + k]));
        m1 = fmaxf(m1, fabsf(Whh1[r * HID + k]));
    }
    qs0[r] = 127.f / m0;   dq0s[r] = m0 / 16129.f * LOG2E;
    qs1[r] = 127.f / m1;   dq1s[r] = m1 / 16129.f * LOG2E;
    b0s[r] = (bih0[r] + bhh0[r]) * LOG2E;
    b1s[r] = (bih1[r] + bhh1[r]) * LOG2E;
}

// ---------------------------------------------------------------------------
// prep_b: i8 frag packs for Whh0/Whh1; bf16 Wih1 frags (x LOG2E); w0c = plain
// [NG][8] bf16 Wih0 x LOG2E (rec0 reads rows directly, no MFMA); x padded;
// zeroed states.
// ---------------------------------------------------------------------------
__global__ void prep_b(const float* __restrict__ x,
    const float* __restrict__ Wih0, const float* __restrict__ Whh0,
    const float* __restrict__ Wih1, const float* __restrict__ Whh1,
    const float* __restrict__ qs0, const float* __restrict__ qs1,
    i8* __restrict__ wi80, i8* __restrict__ wi81,
    u16* __restrict__ wih1f, u16* __restrict__ w0c,
    i8* __restrict__ hs0, i8* __restrict__ hs1,
    float* __restrict__ cs0, float* __restrict__ cs1, u16* __restrict__ xpad)
{
    const int stride = gridDim.x * blockDim.x;
    const int tid = blockIdx.x * blockDim.x + threadIdx.x;
    for (int i = tid; i < NG * HID; i += stride) {   // i8 packs (recurrent)
        int e = i & 15, l = (i >> 4) & 63, kc = (i >> 10) & 3, gt = i >> 12;
        int row = 16 * gt + (l & 15);
        int k = kc * 64 + (l >> 4) * 16 + e;
        float q0 = __builtin_rintf(Whh0[row * HID + k] * qs0[row]);
        float q1 = __builtin_rintf(Whh1[row * HID + k] * qs1[row]);
        wi80[i] = (i8)fminf(fmaxf(q0, -127.f), 127.f);
        wi81[i] = (i8)fminf(fmaxf(q1, -127.f), 127.f);
    }
    for (int i = tid; i < NG * HID; i += stride) {   // Wih1 bf16 frags, scaled
        int gt = i >> 12, kk = (i >> 9) & 7, l = (i >> 3) & 63, e = i & 7;
        wih1f[i] = f2bf(Wih1[(16 * gt + (l & 15)) * HID + kk * 32 + (l >> 4) * 8 + e] * LOG2E);
    }
    for (int i = tid; i < NG * 8; i += stride) {     // Wih0 rows, scaled, pad 5->8
        int r = i >> 3, k = i & 7;
        w0c[i] = (k < 5) ? f2bf(Wih0[r * 5 + k] * LOG2E) : (u16)0;
    }
    for (int i = tid; i < TSTEPS * BATCH * 8; i += stride) {  // x padded to 8, token-major
        int tok = i >> 3, k = i & 7, t = tok >> 8, b = tok & 255;
        xpad[i] = (k < 5) ? f2bf(x[((size_t)b * TSTEPS + t) * 5 + k]) : (u16)0;
    }
    for (int i = tid; i < BATCH * HID; i += stride) { hs0[i] = 0; hs1[i] = 0; cs0[i] = 0.f; cs1[i] = 0.f; }
}

// ---------------------------------------------------------------------------
// stage_fused(L): three pipeline roles on disjoint blocks:
//   blocks [0,64):    rec layer0, chunk L     (reads x directly, writes h0c)
//   blocks [64,128):  rec layer1, chunk L-2   (reads pre1)
//   blocks [128,192): gemm1: pre1(chunk L-1) = log2e*(Wih1 h0 + b1)
//
// R9 POST-MORTEM: persistent/flag sync = 394MB overfetch from per-chunk L2
// invalidates; reverted to launch-boundary sync (R8). NEW: gemm0 eliminated
// -- IN_DIM=5 means Wih0-x is 20 fmaf/lane, computed in rec0's cell off the
// MFMA critical path (p is independent of the MFMA result). Removes 1 stage
// of pipeline lag (19->18 launches), the 32MB/stage pre0 round-trip, and the
// gemm0 CUs. rec0's input path is now MORE precise (no bf16 pre0 rounding);
// rec1/gemm1 bit-identical to R8.
// ---------------------------------------------------------------------------
__global__ __launch_bounds__(1024) __attribute__((amdgpu_waves_per_eu(4, 4)))
void stage_fused(int L,
    const u16* __restrict__ xpad8, const u16* __restrict__ w0c, const float* __restrict__ b0s,
    const u16* __restrict__ wih1f, const float* __restrict__ b1s,
    u16* __restrict__ h0w, const u16* __restrict__ h0r,
    u16* __restrict__ p1w, const u16* __restrict__ p1r,
    const i8* __restrict__ wi80, const i8* __restrict__ wi81,
    const float* __restrict__ dq0s, const float* __restrict__ dq1s,
    i8* __restrict__ hs0, i8* __restrict__ hs1,
    float* __restrict__ cs0, float* __restrict__ cs1)
{
    __shared__ __align__(16) char smem[16384];   // gemm1: 2x8KB A dbuf; rec: 2x1152B h_lds
    const int bid = blockIdx.x;
    const int tid = threadIdx.x, lane = tid & 63;
    const int col = lane & 15, kgrp = lane >> 4;

    if (bid < GB1) {
        // ---------------- recurrent roles (BB=4) ----------------
        const int layer = bid >> 6;
        const int btile = bid & 63;
        i8 (*h_lds)[BB * HSTR] = (i8 (*)[BB * HSTR])smem;
        const int w = tid >> 6;
        const int b0 = btile * BB;
        const int u = w * 16 + col;          // h-unit this lane owns

        if (layer == 0) {
            if (L >= NCH) return;
            float sc[4], pbias[4], w0r[4][5];
            i32x4 wv[4][4];                  // 64 VGPRs resident weights
#pragma unroll
            for (int j = 0; j < 4; j++) {
                const int gt = 16 * j + w;
                sc[j] = dq0s[gt * 16 + col];
                pbias[j] = b0s[gt * 16 + col];
                bf16x8 wrow = *(const bf16x8*)&w0c[(j * 256 + u) * 8];
#pragma unroll
                for (int k = 0; k < 5; k++) w0r[j][k] = bf2f((u16)wrow[k]);
#pragma unroll
                for (int kc = 0; kc < 4; kc++)
                    wv[j][kc] = ((const i32x4*)wi80)[(gt * 4 + kc) * 64 + lane];
            }
            if (tid < 64 * BB) {
                const int rrow = tid >> 6, cc = (tid & 63) * 4;
                *(int*)&h_lds[0][rrow * HSTR + cc] = *(const int*)&hs0[(b0 + rrow) * HID + cc];
            }
            float c_reg = cs0[(size_t)(b0 + kgrp) * HID + u];
            // x base for this lane's batch: xpad[(L*CH + t)*256 + b][8]
            const u16* xb = xpad8 + (((size_t)L * CH) * 256 + (b0 + kgrp)) * 8;
            bf16x8 xvA, xvB;
            xvA = *(const bf16x8*)&xb[0];
            const size_t h0base = ((((size_t)(w >> 1) * 16 + (btile >> 2)) * 4
                                   + ((w & 1) * 2 + (col >> 3))) * 16
                                  + ((btile & 3) * 4 + kgrp)) * 8 + (col & 7);
            __syncthreads();

#define REC_STEP0(T, CUR, XC, XN) do {                                              \
        _Pragma("unroll")                                                           \
        for (int j = 0; j < 4; j++)                                                 \
            asm volatile("" : "+v"(wv[j][0]), "+v"(wv[j][1]),                       \
                              "+v"(wv[j][2]), "+v"(wv[j][3]));                      \
        i32x4 acc[4];                                                               \
        _Pragma("unroll")                                                           \
        for (int j = 0; j < 4; j++) acc[j] = (i32x4){0, 0, 0, 0};                   \
        _Pragma("unroll")                                                           \
        for (int kc = 0; kc < 4; kc++) {                                            \
            i32x4 a_ = *(const i32x4*)&h_lds[CUR][(col >> 2) * HSTR + kc * 64 + kgrp * 16]; \
            _Pragma("unroll")                                                       \
            for (int j = 0; j < 4; j++) acc[j] = MFMA_I8(a_, wv[j][kc], acc[j]);    \
        }                                                                           \
        const int tn_ = ((T) + 1 < CH) ? (T) + 1 : (T);                             \
        XN = *(const bf16x8*)&xb[(size_t)tn_ * 2048];                               \
        float xf[5], p[4];                                                          \
        _Pragma("unroll")                                                           \
        for (int k = 0; k < 5; k++) xf[k] = bf2f((u16)XC[k]);                       \
        _Pragma("unroll")                                                           \
        for (int j = 0; j < 4; j++) {                                               \
            p[j] = pbias[j];                                                        \
            _Pragma("unroll")                                                       \
            for (int k = 0; k < 5; k++) p[j] = fmaf(w0r[j][k], xf[k], p[j]);        \
        }                                                                           \
        const float yi = fmaf((float)acc[0][0], sc[0], p[0]);                       \
        const float yf = fmaf((float)acc[1][0], sc[1], p[1]);                       \
        const float yg = fmaf((float)acc[2][0], sc[2], p[2]);                       \
        const float yo = fmaf((float)acc[3][0], sc[3], p[3]);                       \
        const float iv = sigm2(yi), fv = sigm2(yf), ov = sigm2(yo);                 \
        const float gv = tanh2(yg + yg);                                            \
        const float cn = fmaf(fv, c_reg, iv * gv);                                  \
        c_reg = cn;                                                                 \
        const float hv = ov * tanh2(cn * (2.f * LOG2E));                            \
        h_lds[(CUR) ^ 1][kgrp * HSTR + u] = (i8)__float2int_rn(hv * 127.f);         \
        h0w[h0base + (size_t)(T) * H0C_TSTR] = f2bf(hv);                            \
        asm volatile("s_waitcnt lgkmcnt(0)" ::: "memory");                          \
        __builtin_amdgcn_s_barrier();                                               \
        __builtin_amdgcn_sched_barrier(0);                                          \
    } while (0)

#pragma unroll 1
            for (int t2 = 0; t2 < CH; t2 += 2) {
                REC_STEP0(t2,     0, xvA, xvB);
                REC_STEP0(t2 + 1, 1, xvB, xvA);
            }
#undef REC_STEP0

            cs0[(size_t)(b0 + kgrp) * HID + u] = c_reg;
            if (tid < 64 * BB) {
                const int rrow = tid >> 6, cc = (tid & 63) * 4;
                *(int*)&hs0[(b0 + rrow) * HID + cc] = *(const int*)&h_lds[0][rrow * HSTR + cc];
            }
        } else {
            if (L < 2 || L > NCH + 1) return;
            float sc[4];
            i32x4 wv[4][4];                  // 64 VGPRs resident weights
#pragma unroll
            for (int j = 0; j < 4; j++) {
                const int gt = 16 * j + w;
                sc[j] = dq1s[gt * 16 + col];
#pragma unroll
                for (int kc = 0; kc < 4; kc++)
                    wv[j][kc] = ((const i32x4*)wi81)[(gt * 4 + kc) * 64 + lane];
            }
            if (tid < 64 * BB) {
                const int rrow = tid >> 6, cc = (tid & 63) * 4;
                *(int*)&h_lds[0][rrow * HSTR + cc] = *(const int*)&hs1[(b0 + rrow) * HID + cc];
            }
            float c_reg = cs1[(size_t)(b0 + kgrp) * HID + u];
            const u16* pb = p1r + ((size_t)btile << 12) + (u << 2) + kgrp;
            u16 pvA[4], pvB[4];
#pragma unroll
            for (int j = 0; j < 4; j++) pvA[j] = pb[j << 10];
            __syncthreads();

#define REC_STEP1(T, CUR, PVC, PVN) do {                                            \
        _Pragma("unroll")                                                           \
        for (int j = 0; j < 4; j++)                                                 \
            asm volatile("" : "+v"(wv[j][0]), "+v"(wv[j][1]),                       \
                              "+v"(wv[j][2]), "+v"(wv[j][3]));                      \
        i32x4 acc[4];                                                               \
        _Pragma("unroll")                                                           \
        for (int j = 0; j < 4; j++) acc[j] = (i32x4){0, 0, 0, 0};                   \
        _Pragma("unroll")                                                           \
        for (int kc = 0; kc < 4; kc++) {                                            \
            i32x4 a_ = *(const i32x4*)&h_lds[CUR][(col >> 2) * HSTR + kc * 64 + kgrp * 16]; \
            _Pragma("unroll")                                                       \
            for (int j = 0; j < 4; j++) acc[j] = MFMA_I8(a_, wv[j][kc], acc[j]);    \
        }                                                                           \
        const int tn_ = ((T) + 1 < CH) ? (T) + 1 : (T);                             \
        _Pragma("unroll")                                                           \
        for (int j = 0; j < 4; j++) PVN[j] = pb[(size_t)tn_ * PRE_TSTR + (j << 10)];\
        const float yi = fmaf((float)acc[0][0], sc[0], bf2f(PVC[0]));               \
        const float yf = fmaf((float)acc[1][0], sc[1], bf2f(PVC[1]));               \
        const float yg = fmaf((float)acc[2][0], sc[2], bf2f(PVC[2]));               \
        const float yo = fmaf((float)acc[3][0], sc[3], bf2f(PVC[3]));               \
        const float iv = sigm2(yi), fv = sigm2(yf), ov = sigm2(yo);                 \
        const float gv = tanh2(yg + yg);                                            \
        const float cn = fmaf(fv, c_reg, iv * gv);                                  \
        c_reg = cn;                                                                 \
        const float hv = ov * tanh2(cn * (2.f * LOG2E));                            \
        h_lds[(CUR) ^ 1][kgrp * HSTR + u] = (i8)__float2int_rn(hv * 127.f);         \
        asm volatile("s_waitcnt lgkmcnt(0)" ::: "memory");                          \
        __builtin_amdgcn_s_barrier();                                               \
        __builtin_amdgcn_sched_barrier(0);                                          \
    } while (0)

#pragma unroll 1
            for (int t2 = 0; t2 < CH; t2 += 2) {
                REC_STEP1(t2,     0, pvA, pvB);
                REC_STEP1(t2 + 1, 1, pvB, pvA);
            }
#undef REC_STEP1

            cs1[(size_t)(b0 + kgrp) * HID + u] = c_reg;
            if (tid < 64 * BB) {
                const int rrow = tid >> 6, cc = (tid & 63) * 4;
                *(int*)&hs1[(b0 + rrow) * HID + cc] = *(const int*)&h_lds[0][rrow * HSTR + cc];
            }
        }
        return;
    } else {
        // ---------------- gemm1: pre1(chunk L-1), 64 blocks x 2 tp, LDS-staged A ----------------
        if (L < 1 || L > NCH) return;
        const int g = bid - GB1;             // 0..63
        const int j = g & 3;                 // j-chunk 0..3
        const int tpb = (g >> 2) * 2;        // t' base: 0,2,..,30
        const int w = tid >> 6;              // wave = 16-gate tile within j
        const int gt = j * 16 + w;           // global 16-gate tile
        const float bias = b1s[gt * 16 + col];
        bf16x8 wv8[8];                       // 32 VGPRs resident weights
#pragma unroll
        for (int kk = 0; kk < 8; kk++)
            wv8[kk] = *(const bf16x8*)&wih1f[((size_t)(gt * 8 + kk) * 64 + lane) * 8];
        u16* As = (u16*)smem;                // [2][8][512] u16 double buffer
        const int kks = tid >> 7;            // staging slice: kk
        const int e4 = (tid & 127) * 4;      // 4 elements (8B) per thread
#pragma unroll 1
        for (int tpi = 0; tpi < 2; tpi++) {
            const int tp = tpb + tpi;
            const u16* Asrc = h0r + (size_t)tp * H0C_TSTR;
            {   // prologue: stage bt=0 into buf0
                u32x2 st = *(const u32x2*)&Asrc[((size_t)kks * 16 + 0) * 512 + e4];
                *(u32x2*)&As[kks * 512 + e4] = st;
            }
            __syncthreads();
#pragma unroll 1
            for (int bt = 0; bt < 16; bt++) {
                const int cur = bt & 1, nxt = cur ^ 1;
                u32x2 nx;
                if (bt + 1 < 16)   // issue next tile's global load early (hidden under MFMA)
                    nx = *(const u32x2*)&Asrc[((size_t)kks * 16 + bt + 1) * 512 + e4];
                bf16x8 a8[8];
#pragma unroll
                for (int kk = 0; kk < 8; kk++)
                    a8[kk] = *(const bf16x8*)&As[cur * 4096 + kk * 512 + lane * 8];
                f32x4 acc = (f32x4){bias, bias, bias, bias};
#pragma unroll
                for (int kk = 0; kk < 8; kk++)
                    acc = MFMA_BF16(a8[kk], wv8[kk], acc);
                const int ul = w * 16 + col;     // u within j-chunk
                const size_t off = ((((size_t)tp * 64 + bt * 4 + kgrp) * 4 + j) << 10) + (ul << 2);
                u32x2 pk;
                pk.x = (unsigned)f2bf(acc[0]) | ((unsigned)f2bf(acc[1]) << 16);
                pk.y = (unsigned)f2bf(acc[2]) | ((unsigned)f2bf(acc[3]) << 16);
                *(u32x2*)&p1w[off] = pk;
                if (bt + 1 < 16)
                    *(u32x2*)&As[nxt * 4096 + kks * 512 + e4] = nx;
                __syncthreads();                 // nxt fully written; cur reads done
            }
        }
        return;
    }
}

// ---------------------------------------------------------------------------
// head: y = sigmoid(relu(h_last) @ Wh^T + bh)
// ---------------------------------------------------------------------------
__global__ void head_kernel(const i8* __restrict__ hs1,
                            const float* __restrict__ Wh, const float* __restrict__ bh,
                            float* __restrict__ y) {
    int b = blockIdx.x;
    int l = threadIdx.x;
    const float inv127 = 1.f / 127.f;
    float hr[4];
#pragma unroll
    for (int i = 0; i < 4; ++i) hr[i] = fmaxf((float)hs1[b * HID + l + 64 * i] * inv127, 0.f);
    for (int o = 0; o < 3; ++o) {
        float s = 0.f;
#pragma unroll
        for (int i = 0; i < 4; ++i) s += hr[i] * Wh[o * HID + l + 64 * i];
        for (int off = 32; off > 0; off >>= 1) s += __shfl_down(s, off, 64);
        if (l == 0) y[b * 3 + o] = 1.f / (1.f + exp2_(-(s + bh[o]) * LOG2E));
    }
}

extern "C" void kernel_launch(void* const* d_in, const int* in_sizes, int n_in,
                              void* d_out, int out_size, void* d_ws, size_t ws_size,
                              hipStream_t stream) {
    const float* x    = (const float*)d_in[0];
    const float* Wih0 = (const float*)d_in[1];
    const float* Whh0 = (const float*)d_in[2];
    const float* bih0 = (const float*)d_in[3];
    const float* bhh0 = (const float*)d_in[4];
    const float* Wih1 = (const float*)d_in[5];
    const float* Whh1 = (const float*)d_in[6];
    const float* bih1 = (const float*)d_in[7];
    const float* bhh1 = (const float*)d_in[8];
    const float* Wh   = (const float*)d_in[9];
    const float* bh   = (const float*)d_in[10];

    char* ws = (char*)d_ws;
    i8*    wi80  = (i8*)(ws);                            // 256 KB
    i8*    wi81  = (i8*)(ws + ((size_t)256 << 10));      // 256 KB
    u16*   wih1f = (u16*)(ws + ((size_t)512 << 10));     // 512 KB
    u16*   w0c   = (u16*)(ws + ((size_t)1024 << 10));    // 16 KB [NG][8] bf16
    float* qs0   = (float*)(ws + ((size_t)1088 << 10));
    float* dq0s  = (float*)(ws + ((size_t)1092 << 10));
    float* qs1   = (float*)(ws + ((size_t)1096 << 10));
    float* dq1s  = (float*)(ws + ((size_t)1100 << 10));
    float* b0s   = (float*)(ws + ((size_t)1104 << 10));
    float* b1s   = (float*)(ws + ((size_t)1108 << 10));
    i8*    hs0   = (i8*)(ws + ((size_t)1112 << 10));     // 64 KB
    i8*    hs1   = (i8*)(ws + ((size_t)1176 << 10));     // 64 KB
    float* cs0   = (float*)(ws + ((size_t)1240 << 10));  // 256 KB
    float* cs1   = (float*)(ws + ((size_t)1496 << 10));  // 256 KB
    u16*   xpad  = (u16*)(ws + ((size_t)1752 << 10));    // 2 MB  [tok][8] bf16
    u16*   h0c   = (u16*)(ws + ((size_t)4096 << 10));    // 2 x 4 MB (chunk parity)
    u16*   pre1  = (u16*)(ws + ((size_t)12288 << 10));   // 2 x 16 MB -> total ~44 MB
    const size_t PRE_ELE = (size_t)CH * BATCH * NG;      // 8 Mi elements (16 MB)
    const size_t H0C_ELE = (size_t)CH * BATCH * HID;     // 2 Mi elements (4 MB)

    prep_a<<<4, 256, 0, stream>>>(Whh0, Whh1, bih0, bhh0, bih1, bhh1,
                                  qs0, dq0s, qs1, dq1s, b0s, b1s);
    prep_b<<<1024, 256, 0, stream>>>(x, Wih0, Whh0, Wih1, Whh1, qs0, qs1,
                                     wi80, wi81, wih1f, w0c, hs0, hs1, cs0, cs1, xpad);
    // pipeline: rec0(c=L) | gemm1(c=L-1) | rec1(c=L-2)
    for (int L = 0; L <= NCH + 1; L++) {
        stage_fused<<<NBLK, 1024, 0, stream>>>(L, xpad, w0c, b0s, wih1f, b1s,
            h0c  + (size_t)(L & 1) * H0C_ELE,        // rec0 writes chunk L     (parity L)
            h0c  + (size_t)((L + 1) & 1) * H0C_ELE,  // gemm1 reads chunk L-1   (parity L-1)
            pre1 + (size_t)((L + 1) & 1) * PRE_ELE,  // gemm1 writes chunk L-1
            pre1 + (size_t)(L & 1) * PRE_ELE,        // rec1 reads chunk L-2    (parity L)
            wi80, wi81, dq0s, dq1s, hs0, hs1, cs0, cs1);
    }
    head_kernel<<<BATCH, 64, 0, stream>>>(hs1, Wh, bh, (float*)d_out);
}

// Round 11
// 565.635 us; speedup vs baseline: 1.5176x; 1.3679x over previous
//
#include <hip/hip_runtime.h>
#include <hip/hip_bf16.h>

typedef unsigned short u16;
typedef signed char i8;
typedef __attribute__((ext_vector_type(4))) float f32x4;
typedef __attribute__((ext_vector_type(4))) int i32x4;
typedef __attribute__((ext_vector_type(8))) short bf16x8;
typedef __attribute__((ext_vector_type(2))) unsigned int u32x2;

#define HID 256
#define NG 1024
#define TSTEPS 512
#define BATCH 256
#define CH 32          // steps per chunk (R8-proven optimum)
#define NCH 16         // chunks (CH*NCH = 512)
#define BB 4           // batch rows per rec block (1 cell/lane via A-row duplication)
#define HSTR 288       // h_lds row stride bytes
#define LOG2E 1.4426950408889634f
#define PRE_TSTR 262144   // per-t' element stride in pre: 64 btiles * 4 j * 1024 (u*4+kb)
#define H0C_TSTR 65536    // per-t element stride in h0c frag layout [kk][bt][kgrp][col][e]

// fused-stage block roles (exact R8 = best measured, 566us)
#define GB0 128        // gemm0 blocks [128,160)
#define GB1 160        // gemm1 blocks [160,224)
#define NBLK 224

#define MFMA_BF16(a, b, c) __builtin_amdgcn_mfma_f32_16x16x32_bf16((a), (b), (c), 0, 0, 0)
#define MFMA_I8(a, b, c)   __builtin_amdgcn_mfma_i32_16x16x64_i8((a), (b), (c), 0, 0, 0)

__device__ __forceinline__ float rcpf_(float x) {
#if __has_builtin(__builtin_amdgcn_rcpf)
    return __builtin_amdgcn_rcpf(x);
#else
    return 1.f / x;
#endif
}
__device__ __forceinline__ float exp2_(float x) {
#if __has_builtin(__builtin_amdgcn_exp2f)
    return __builtin_amdgcn_exp2f(x);
#else
    return exp2f(x);
#endif
}
__device__ __forceinline__ float sigm2(float y) { return rcpf_(1.f + exp2_(-y)); }
__device__ __forceinline__ float tanh2(float y2) { return fmaf(-2.f, rcpf_(exp2_(y2) + 1.f), 1.f); }
__device__ __forceinline__ u16 f2bf(float v){ __hip_bfloat16 h=__float2bfloat16(v); return __builtin_bit_cast(u16,h); }
__device__ __forceinline__ float bf2f(u16 u){ unsigned x=((unsigned)u)<<16; return __builtin_bit_cast(float,x); }

// ---------------------------------------------------------------------------
// prep_a (R10 post-mortem rework): wave-per-row coalesced row-max. Old version
// had each thread serially reading a 1KB-strided row (256 uncoalesced lines
// per iter, ~20-30us). Now each wave reads a full row as 64x16B coalesced and
// max-reduces via shfl_xor butterfly. Max is exactly associative/commutative
// -> bit-identical scales. 16 blocks x 256 thr = 64 waves x 16 rows.
// ---------------------------------------------------------------------------
__global__ void prep_a(const float* __restrict__ Whh0, const float* __restrict__ Whh1,
                       const float* __restrict__ bih0, const float* __restrict__ bhh0,
                       const float* __restrict__ bih1, const float* __restrict__ bhh1,
                       float* __restrict__ qs0, float* __restrict__ dq0s,
                       float* __restrict__ qs1, float* __restrict__ dq1s,
                       float* __restrict__ b0s, float* __restrict__ b1s) {
    const int tid = blockIdx.x * blockDim.x + threadIdx.x;
    const int wave = tid >> 6, lane = tid & 63;
#pragma unroll 1
    for (int rr = 0; rr < 16; rr++) {
        const int r = wave * 16 + rr;
        f32x4 v0 = *(const f32x4*)&Whh0[(size_t)r * HID + lane * 4];
        f32x4 v1 = *(const f32x4*)&Whh1[(size_t)r * HID + lane * 4];
        float m0 = 1e-20f, m1 = 1e-20f;
#pragma unroll
        for (int k = 0; k < 4; k++) {
            m0 = fmaxf(m0, fabsf(v0[k]));
            m1 = fmaxf(m1, fabsf(v1[k]));
        }
#pragma unroll
        for (int off = 32; off > 0; off >>= 1) {
            m0 = fmaxf(m0, __shfl_xor(m0, off, 64));
            m1 = fmaxf(m1, __shfl_xor(m1, off, 64));
        }
        if (lane == 0) {
            qs0[r] = 127.f / m0;   dq0s[r] = m0 / 16129.f * LOG2E;
            qs1[r] = 127.f / m1;   dq1s[r] = m1 / 16129.f * LOG2E;
            b0s[r] = (bih0[r] + bhh0[r]) * LOG2E;
            b1s[r] = (bih1[r] + bhh1[r]) * LOG2E;
        }
    }
}

// ---------------------------------------------------------------------------
// prep_b: i8 frag packs for Whh0/Whh1; bf16 Wih1 frags (x LOG2E); bf16 Wih0
// frags (x LOG2E, K pad 5->32); x padded to 8 bf16/token; zeroed states.
// (exact R8)
// ---------------------------------------------------------------------------
__global__ void prep_b(const float* __restrict__ x,
    const float* __restrict__ Wih0, const float* __restrict__ Whh0,
    const float* __restrict__ Wih1, const float* __restrict__ Whh1,
    const float* __restrict__ qs0, const float* __restrict__ qs1,
    i8* __restrict__ wi80, i8* __restrict__ wi81,
    u16* __restrict__ wih1f, u16* __restrict__ wih0f,
    i8* __restrict__ hs0, i8* __restrict__ hs1,
    float* __restrict__ cs0, float* __restrict__ cs1, u16* __restrict__ xpad)
{
    const int stride = gridDim.x * blockDim.x;
    const int tid = blockIdx.x * blockDim.x + threadIdx.x;
    for (int i = tid; i < NG * HID; i += stride) {   // i8 packs (recurrent)
        int e = i & 15, l = (i >> 4) & 63, kc = (i >> 10) & 3, gt = i >> 12;
        int row = 16 * gt + (l & 15);
        int k = kc * 64 + (l >> 4) * 16 + e;
        float q0 = __builtin_rintf(Whh0[row * HID + k] * qs0[row]);
        float q1 = __builtin_rintf(Whh1[row * HID + k] * qs1[row]);
        wi80[i] = (i8)fminf(fmaxf(q0, -127.f), 127.f);
        wi81[i] = (i8)fminf(fmaxf(q1, -127.f), 127.f);
    }
    for (int i = tid; i < NG * HID; i += stride) {   // Wih1 bf16 frags, scaled
        int gt = i >> 12, kk = (i >> 9) & 7, l = (i >> 3) & 63, e = i & 7;
        wih1f[i] = f2bf(Wih1[(16 * gt + (l & 15)) * HID + kk * 32 + (l >> 4) * 8 + e] * LOG2E);
    }
    for (int i = tid; i < 32768; i += stride) {      // Wih0 bf16 frags, scaled
        int gt = i >> 9, l = (i >> 3) & 63, e = i & 7;
        int k = (l >> 4) * 8 + e;
        wih0f[i] = (k < 5) ? f2bf(Wih0[(16 * gt + (l & 15)) * 5 + k] * LOG2E) : (u16)0;
    }
    for (int i = tid; i < TSTEPS * BATCH * 8; i += stride) {  // x padded to 8, token-major
        int tok = i >> 3, k = i & 7, t = tok >> 8, b = tok & 255;
        xpad[i] = (k < 5) ? f2bf(x[((size_t)b * TSTEPS + t) * 5 + k]) : (u16)0;
    }
    for (int i = tid; i < BATCH * HID; i += stride) { hs0[i] = 0; hs1[i] = 0; cs0[i] = 0.f; cs1[i] = 0.f; }
}

// ---------------------------------------------------------------------------
// stage_fused(L): four pipeline roles on disjoint blocks (exact R8, 566us):
//   blocks [0,64):    rec layer0, chunk L-1   (reads pre0, writes h0c)
//   blocks [64,128):  rec layer1, chunk L-3   (reads pre1)
//   blocks [128,160): gemm0: pre0(chunk L)   = log2e*(Wih0 x + b0)
//   blocks [160,224): gemm1: pre1(chunk L-2) = log2e*(Wih1 h0 + b1)
// R9 (persistent/flag-sync) and R10 (gemm0 folded into rec0) both regressed;
// launch-boundary sync with this 4-role split is the best-measured structure.
// ---------------------------------------------------------------------------
__global__ __launch_bounds__(1024) __attribute__((amdgpu_waves_per_eu(4, 4)))
void stage_fused(int L,
    const u16* __restrict__ xpad8, const u16* __restrict__ wih0f, const float* __restrict__ b0s,
    const u16* __restrict__ wih1f, const float* __restrict__ b1s,
    u16* __restrict__ p0w, const u16* __restrict__ p0r,
    u16* __restrict__ h0w, const u16* __restrict__ h0r,
    u16* __restrict__ p1w, const u16* __restrict__ p1r,
    const i8* __restrict__ wi80, const i8* __restrict__ wi81,
    const float* __restrict__ dq0s, const float* __restrict__ dq1s,
    i8* __restrict__ hs0, i8* __restrict__ hs1,
    float* __restrict__ cs0, float* __restrict__ cs1)
{
    __shared__ __align__(16) char smem[16384];   // gemm1: 2x8KB A dbuf; rec: 2x1152B h_lds
    const int bid = blockIdx.x;
    const int tid = threadIdx.x, lane = tid & 63;
    const int col = lane & 15, kgrp = lane >> 4;

    if (bid < GB0) {
        // ---------------- recurrent role (BB=4) ----------------
        const int layer = bid >> 6;
        if (layer == 0) { if (L < 1 || L > NCH) return; }
        else            { if (L < 3 || L > NCH + 2) return; }
        i8 (*h_lds)[BB * HSTR] = (i8 (*)[BB * HSTR])smem;
        const int btile = bid & 63;
        const u16* pre   = layer ? p1r : p0r;
        const i8*  wi8   = layer ? wi81 : wi80;
        const float* dq  = layer ? dq1s : dq0s;
        i8*    h_state   = layer ? hs1 : hs0;
        float* c_state   = layer ? cs1 : cs0;
        const int w = tid >> 6;
        const int b0 = btile * BB;
        const int u = w * 16 + col;          // h-unit this lane owns

        float sc[4];
        i32x4 wv[4][4];                      // 64 regs resident weights
#pragma unroll
        for (int j = 0; j < 4; j++) {
            const int gt = 16 * j + w;
            sc[j] = dq[gt * 16 + col];
#pragma unroll
            for (int kc = 0; kc < 4; kc++)
                wv[j][kc] = ((const i32x4*)wi8)[(gt * 4 + kc) * 64 + lane];
        }
        if (tid < 64 * BB) {
            const int rrow = tid >> 6, cc = (tid & 63) * 4;
            *(int*)&h_lds[0][rrow * HSTR + cc] = *(const int*)&h_state[(b0 + rrow) * HID + cc];
        }
        float c_reg = c_state[(size_t)(b0 + kgrp) * HID + u];

        // pre base for this lane: btile*4096 + u*4 + kgrp   (contiguous per wave)
        const u16* pb = pre + ((size_t)btile << 12) + (u << 2) + kgrp;
        u16 pvA[4], pvB[4];
#pragma unroll
        for (int j = 0; j < 4; j++) pvA[j] = pb[j << 10];
        // h0c store base in frag layout [t][kk=u>>5][bt=btile>>2][kgrpg=(u>>3)&3][colg][e=u&7]
        const size_t h0base = ((((size_t)(w >> 1) * 16 + (btile >> 2)) * 4
                               + ((w & 1) * 2 + (col >> 3))) * 16
                              + ((btile & 3) * 4 + kgrp)) * 8 + (col & 7);
        __syncthreads();

#define REC_STEP(T, CUR, PVC, PVN) do {                                             \
        _Pragma("unroll")                                                           \
        for (int j = 0; j < 4; j++)                                                 \
            asm volatile("" : "+v"(wv[j][0]), "+v"(wv[j][1]),                       \
                              "+v"(wv[j][2]), "+v"(wv[j][3]));                      \
        i32x4 acc[4];                                                               \
        _Pragma("unroll")                                                           \
        for (int j = 0; j < 4; j++) acc[j] = (i32x4){0, 0, 0, 0};                   \
        _Pragma("unroll")                                                           \
        for (int kc = 0; kc < 4; kc++) {                                            \
            i32x4 a_ = *(const i32x4*)&h_lds[CUR][(col >> 2) * HSTR + kc * 64 + kgrp * 16]; \
            _Pragma("unroll")                                                       \
            for (int j = 0; j < 4; j++) acc[j] = MFMA_I8(a_, wv[j][kc], acc[j]);    \
        }                                                                           \
        const int tn_ = ((T) + 1 < CH) ? (T) + 1 : (T);                             \
        _Pragma("unroll")                                                           \
        for (int j = 0; j < 4; j++) PVN[j] = pb[(size_t)tn_ * PRE_TSTR + (j << 10)];\
        const float yi = fmaf((float)acc[0][0], sc[0], bf2f(PVC[0]));               \
        const float yf = fmaf((float)acc[1][0], sc[1], bf2f(PVC[1]));               \
        const float yg = fmaf((float)acc[2][0], sc[2], bf2f(PVC[2]));               \
        const float yo = fmaf((float)acc[3][0], sc[3], bf2f(PVC[3]));               \
        const float iv = sigm2(yi), fv = sigm2(yf), ov = sigm2(yo);                 \
        const float gv = tanh2(yg + yg);                                            \
        const float cn = fmaf(fv, c_reg, iv * gv);                                  \
        c_reg = cn;                                                                 \
        const float hv = ov * tanh2(cn * (2.f * LOG2E));                            \
        h_lds[(CUR) ^ 1][kgrp * HSTR + u] = (i8)__float2int_rn(hv * 127.f);         \
        if (layer == 0)                                                             \
            h0w[h0base + (size_t)(T) * H0C_TSTR] = f2bf(hv);                        \
        asm volatile("s_waitcnt lgkmcnt(0)" ::: "memory");                          \
        __builtin_amdgcn_s_barrier();                                               \
        __builtin_amdgcn_sched_barrier(0);                                          \
    } while (0)

#pragma unroll 1
        for (int t2 = 0; t2 < CH; t2 += 2) {
            REC_STEP(t2,     0, pvA, pvB);
            REC_STEP(t2 + 1, 1, pvB, pvA);
        }
#undef REC_STEP

        c_state[(size_t)(b0 + kgrp) * HID + u] = c_reg;
        if (tid < 64 * BB) {
            const int rrow = tid >> 6, cc = (tid & 63) * 4;
            *(int*)&h_state[(b0 + rrow) * HID + cc] = *(const int*)&h_lds[0][rrow * HSTR + cc];
        }
        return;
    } else if (bid < GB1) {
        // ---------------- gemm0: pre0(chunk L), 32 blocks x 1 tp x 16 bt ----------------
        if (L >= NCH) return;
        const int tp = bid - GB0;            // t' 0..31
        const int w = tid >> 6;              // wave 0..15
        const int j = w >> 2;                // pre j-chunk, constant per wave
        float bias[4];
        bf16x8 wv4[4];
#pragma unroll
        for (int tm = 0; tm < 4; tm++) {
            const int tile = w * 4 + tm;     // 16-gate tile 0..63
            bias[tm] = b0s[tile * 16 + col];
            wv4[tm] = *(const bf16x8*)&wih0f[((size_t)tile * 64 + lane) * 8];
        }
        const u16* Ab = xpad8 + ((size_t)L * CH + tp) * BATCH * 8;
#pragma unroll 1
        for (int btg = 0; btg < 16; btg++) {
            bf16x8 af = {0, 0, 0, 0, 0, 0, 0, 0};   // K beyond 8 is zero-padded
            if (kgrp == 0) af = *(const bf16x8*)&Ab[(btg * 16 + col) * 8];
            f32x4 acc[4];
#pragma unroll
            for (int tm = 0; tm < 4; tm++) acc[tm] = (f32x4){bias[tm], bias[tm], bias[tm], bias[tm]};
#pragma unroll
            for (int tm = 0; tm < 4; tm++) acc[tm] = MFMA_BF16(af, wv4[tm], acc[tm]);
            // batch = btg*16+kgrp*4+rr -> (btile = btg*4+kgrp, kb = rr): one 8B store.
#pragma unroll
            for (int tm = 0; tm < 4; tm++) {
                const int ul = ((w & 3) * 4 + tm) * 16 + col;   // u within j-chunk
                const size_t off = ((((size_t)tp * 64 + btg * 4 + kgrp) * 4 + j) << 10) + (ul << 2);
                u32x2 pk;
                pk.x = (unsigned)f2bf(acc[tm][0]) | ((unsigned)f2bf(acc[tm][1]) << 16);
                pk.y = (unsigned)f2bf(acc[tm][2]) | ((unsigned)f2bf(acc[tm][3]) << 16);
                *(u32x2*)&p0w[off] = pk;
            }
        }
        return;
    } else {
        // ---------------- gemm1: pre1(chunk L-2), 64 blocks x 2 tp, LDS-staged A ----------------
        if (L < 2 || L > NCH + 1) return;
        const int g = bid - GB1;             // 0..63
        const int j = g & 3;                 // j-chunk 0..3
        const int tpb = (g >> 2) * 2;        // t' base: 0,2,..,30
        const int w = tid >> 6;              // wave = 16-gate tile within j
        const int gt = j * 16 + w;           // global 16-gate tile
        const float bias = b1s[gt * 16 + col];
        bf16x8 wv8[8];                       // 32 regs resident weights
#pragma unroll
        for (int kk = 0; kk < 8; kk++)
            wv8[kk] = *(const bf16x8*)&wih1f[((size_t)(gt * 8 + kk) * 64 + lane) * 8];
        u16* As = (u16*)smem;                // [2][8][512] u16 double buffer
        const int kks = tid >> 7;            // staging slice: kk
        const int e4 = (tid & 127) * 4;      // 4 elements (8B) per thread
#pragma unroll 1
        for (int tpi = 0; tpi < 2; tpi++) {
            const int tp = tpb + tpi;
            const u16* Asrc = h0r + (size_t)tp * H0C_TSTR;
            {   // prologue: stage bt=0 into buf0
                u32x2 st = *(const u32x2*)&Asrc[((size_t)kks * 16 + 0) * 512 + e4];
                *(u32x2*)&As[kks * 512 + e4] = st;
            }
            __syncthreads();
#pragma unroll 1
            for (int bt = 0; bt < 16; bt++) {
                const int cur = bt & 1, nxt = cur ^ 1;
                u32x2 nx;
                if (bt + 1 < 16)   // issue next tile's global load early (hidden under MFMA)
                    nx = *(const u32x2*)&Asrc[((size_t)kks * 16 + bt + 1) * 512 + e4];
                bf16x8 a8[8];
#pragma unroll
                for (int kk = 0; kk < 8; kk++)
                    a8[kk] = *(const bf16x8*)&As[cur * 4096 + kk * 512 + lane * 8];
                f32x4 acc = (f32x4){bias, bias, bias, bias};
#pragma unroll
                for (int kk = 0; kk < 8; kk++)
                    acc = MFMA_BF16(a8[kk], wv8[kk], acc);
                const int ul = w * 16 + col;     // u within j-chunk
                const size_t off = ((((size_t)tp * 64 + bt * 4 + kgrp) * 4 + j) << 10) + (ul << 2);
                u32x2 pk;
                pk.x = (unsigned)f2bf(acc[0]) | ((unsigned)f2bf(acc[1]) << 16);
                pk.y = (unsigned)f2bf(acc[2]) | ((unsigned)f2bf(acc[3]) << 16);
                *(u32x2*)&p1w[off] = pk;
                if (bt + 1 < 16)
                    *(u32x2*)&As[nxt * 4096 + kks * 512 + e4] = nx;
                __syncthreads();                 // nxt fully written; cur reads done
            }
        }
        return;
    }
}

// ---------------------------------------------------------------------------
// head: y = sigmoid(relu(h_last) @ Wh^T + bh)
// ---------------------------------------------------------------------------
__global__ void head_kernel(const i8* __restrict__ hs1,
                            const float* __restrict__ Wh, const float* __restrict__ bh,
                            float* __restrict__ y) {
    int b = blockIdx.x;
    int l = threadIdx.x;
    const float inv127 = 1.f / 127.f;
    float hr[4];
#pragma unroll
    for (int i = 0; i < 4; ++i) hr[i] = fmaxf((float)hs1[b * HID + l + 64 * i] * inv127, 0.f);
    for (int o = 0; o < 3; ++o) {
        float s = 0.f;
#pragma unroll
        for (int i = 0; i < 4; ++i) s += hr[i] * Wh[o * HID + l + 64 * i];
        for (int off = 32; off > 0; off >>= 1) s += __shfl_down(s, off, 64);
        if (l == 0) y[b * 3 + o] = 1.f / (1.f + exp2_(-(s + bh[o]) * LOG2E));
    }
}

extern "C" void kernel_launch(void* const* d_in, const int* in_sizes, int n_in,
                              void* d_out, int out_size, void* d_ws, size_t ws_size,
                              hipStream_t stream) {
    const float* x    = (const float*)d_in[0];
    const float* Wih0 = (const float*)d_in[1];
    const float* Whh0 = (const float*)d_in[2];
    const float* bih0 = (const float*)d_in[3];
    const float* bhh0 = (const float*)d_in[4];
    const float* Wih1 = (const float*)d_in[5];
    const float* Whh1 = (const float*)d_in[6];
    const float* bih1 = (const float*)d_in[7];
    const float* bhh1 = (const float*)d_in[8];
    const float* Wh   = (const float*)d_in[9];
    const float* bh   = (const float*)d_in[10];

    char* ws = (char*)d_ws;
    i8*    wi80  = (i8*)(ws);                            // 256 KB
    i8*    wi81  = (i8*)(ws + ((size_t)256 << 10));      // 256 KB
    u16*   wih1f = (u16*)(ws + ((size_t)512 << 10));     // 512 KB
    u16*   wih0f = (u16*)(ws + ((size_t)1024 << 10));    // 64 KB
    float* qs0   = (float*)(ws + ((size_t)1088 << 10));
    float* dq0s  = (float*)(ws + ((size_t)1092 << 10));
    float* qs1   = (float*)(ws + ((size_t)1096 << 10));
    float* dq1s  = (float*)(ws + ((size_t)1100 << 10));
    float* b0s   = (float*)(ws + ((size_t)1104 << 10));
    float* b1s   = (float*)(ws + ((size_t)1108 << 10));
    i8*    hs0   = (i8*)(ws + ((size_t)1112 << 10));     // 64 KB
    i8*    hs1   = (i8*)(ws + ((size_t)1176 << 10));     // 64 KB
    float* cs0   = (float*)(ws + ((size_t)1240 << 10));  // 256 KB
    float* cs1   = (float*)(ws + ((size_t)1496 << 10));  // 256 KB
    u16*   xpad  = (u16*)(ws + ((size_t)1752 << 10));    // 2 MB  [tok][8] bf16
    u16*   h0c   = (u16*)(ws + ((size_t)4096 << 10));    // 2 x 4 MB (chunk parity)
    u16*   pre0  = (u16*)(ws + ((size_t)12288 << 10));   // 2 x 16 MB (chunk parity)
    u16*   pre1  = (u16*)(ws + ((size_t)45056 << 10));   // 2 x 16 MB -> total ~76 MB
    const size_t PRE_ELE = (size_t)CH * BATCH * NG;      // 8 Mi elements (16 MB)
    const size_t H0C_ELE = (size_t)CH * BATCH * HID;     // 2 Mi elements (4 MB)

    prep_a<<<16, 256, 0, stream>>>(Whh0, Whh1, bih0, bhh0, bih1, bhh1,
                                   qs0, dq0s, qs1, dq1s, b0s, b1s);
    prep_b<<<1024, 256, 0, stream>>>(x, Wih0, Whh0, Wih1, Whh1, qs0, qs1,
                                     wi80, wi81, wih1f, wih0f, hs0, hs1, cs0, cs1, xpad);
    // pipeline: gemm0(c=L) | rec0(c=L-1) | gemm1(c=L-2) | rec1(c=L-3)
    for (int L = 0; L <= NCH + 2; L++) {
        const size_t pA = (size_t)(L & 1), pB = pA ^ 1;
        stage_fused<<<NBLK, 1024, 0, stream>>>(L, xpad, wih0f, b0s, wih1f, b1s,
            pre0 + pA * PRE_ELE,        // gemm0 writes chunk L      (parity L)
            pre0 + pB * PRE_ELE,        // rec0 reads chunk L-1      (parity L-1)
            h0c  + pB * H0C_ELE,        // rec0 writes chunk L-1
            h0c  + pA * H0C_ELE,        // gemm1 reads chunk L-2     (parity L)
            pre1 + pA * PRE_ELE,        // gemm1 writes chunk L-2
            pre1 + pB * PRE_ELE,        // rec1 reads chunk L-3      (parity L-1)
            wi80, wi81, dq0s, dq1s, hs0, hs1, cs0, cs1);
    }
    head_kernel<<<BATCH, 64, 0, stream>>>(hs1, Wh, bh, (float*)d_out);
}

// Round 12
// 558.686 us; speedup vs baseline: 1.5365x; 1.0124x over previous
//
#include <hip/hip_runtime.h>
#include <hip/hip_bf16.h>

typedef unsigned short u16;
typedef signed char i8;
typedef __attribute__((ext_vector_type(4))) float f32x4;
typedef __attribute__((ext_vector_type(4))) int i32x4;
typedef __attribute__((ext_vector_type(8))) short bf16x8;
typedef __attribute__((ext_vector_type(2))) unsigned int u32x2;

#define HID 256
#define NG 1024
#define TSTEPS 512
#define BATCH 256
#define CH 32          // steps per chunk (R8-proven optimum)
#define NCH 16         // chunks (CH*NCH = 512)
#define BB 4           // batch rows per rec block (1 cell/lane via A-row duplication)
#define HSTR 288       // h_lds row stride bytes
#define LOG2E 1.4426950408889634f
#define PRE_TSTR 262144   // per-t' element stride in pre: 64 btiles * 4 j * 1024 (u*4+kb)
#define H0C_TSTR 65536    // per-t element stride in h0c frag layout [kk][bt][kgrp][col][e]

// fused-stage block roles (R8 structure = best measured)
#define GB0 128        // gemm0 blocks [128,160)
#define GB1 160        // gemm1 blocks [160,224)
#define NBLK 224

#define MFMA_BF16(a, b, c) __builtin_amdgcn_mfma_f32_16x16x32_bf16((a), (b), (c), 0, 0, 0)
#define MFMA_I8(a, b, c)   __builtin_amdgcn_mfma_i32_16x16x64_i8((a), (b), (c), 0, 0, 0)

__device__ __forceinline__ float rcpf_(float x) {
#if __has_builtin(__builtin_amdgcn_rcpf)
    return __builtin_amdgcn_rcpf(x);
#else
    return 1.f / x;
#endif
}
__device__ __forceinline__ float exp2_(float x) {
#if __has_builtin(__builtin_amdgcn_exp2f)
    return __builtin_amdgcn_exp2f(x);
#else
    return exp2f(x);
#endif
}
__device__ __forceinline__ float sigm2(float y) { return rcpf_(1.f + exp2_(-y)); }
__device__ __forceinline__ float tanh2(float y2) { return fmaf(-2.f, rcpf_(exp2_(y2) + 1.f), 1.f); }
__device__ __forceinline__ u16 f2bf(float v){ __hip_bfloat16 h=__float2bfloat16(v); return __builtin_bit_cast(u16,h); }
__device__ __forceinline__ float bf2f(u16 u){ unsigned x=((unsigned)u)<<16; return __builtin_bit_cast(float,x); }

// ---------------------------------------------------------------------------
// prep_a: wave-per-row coalesced row-max (R11). Max is exactly associative ->
// bit-identical scales.
// ---------------------------------------------------------------------------
__global__ void prep_a(const float* __restrict__ Whh0, const float* __restrict__ Whh1,
                       const float* __restrict__ bih0, const float* __restrict__ bhh0,
                       const float* __restrict__ bih1, const float* __restrict__ bhh1,
                       float* __restrict__ qs0, float* __restrict__ dq0s,
                       float* __restrict__ qs1, float* __restrict__ dq1s,
                       float* __restrict__ b0s, float* __restrict__ b1s) {
    const int tid = blockIdx.x * blockDim.x + threadIdx.x;
    const int wave = tid >> 6, lane = tid & 63;
#pragma unroll 1
    for (int rr = 0; rr < 16; rr++) {
        const int r = wave * 16 + rr;
        f32x4 v0 = *(const f32x4*)&Whh0[(size_t)r * HID + lane * 4];
        f32x4 v1 = *(const f32x4*)&Whh1[(size_t)r * HID + lane * 4];
        float m0 = 1e-20f, m1 = 1e-20f;
#pragma unroll
        for (int k = 0; k < 4; k++) {
            m0 = fmaxf(m0, fabsf(v0[k]));
            m1 = fmaxf(m1, fabsf(v1[k]));
        }
#pragma unroll
        for (int off = 32; off > 0; off >>= 1) {
            m0 = fmaxf(m0, __shfl_xor(m0, off, 64));
            m1 = fmaxf(m1, __shfl_xor(m1, off, 64));
        }
        if (lane == 0) {
            qs0[r] = 127.f / m0;   dq0s[r] = m0 / 16129.f * LOG2E;
            qs1[r] = 127.f / m1;   dq1s[r] = m1 / 16129.f * LOG2E;
            b0s[r] = (bih0[r] + bhh0[r]) * LOG2E;
            b1s[r] = (bih1[r] + bhh1[r]) * LOG2E;
        }
    }
}

// ---------------------------------------------------------------------------
// prep_b: i8 frag packs for Whh0/Whh1; bf16 Wih1 frags (x LOG2E); bf16 Wih0
// frags (x LOG2E, K pad 5->32); x padded to 8 bf16/token; zeroed states.
// (exact R8)
// ---------------------------------------------------------------------------
__global__ void prep_b(const float* __restrict__ x,
    const float* __restrict__ Wih0, const float* __restrict__ Whh0,
    const float* __restrict__ Wih1, const float* __restrict__ Whh1,
    const float* __restrict__ qs0, const float* __restrict__ qs1,
    i8* __restrict__ wi80, i8* __restrict__ wi81,
    u16* __restrict__ wih1f, u16* __restrict__ wih0f,
    i8* __restrict__ hs0, i8* __restrict__ hs1,
    float* __restrict__ cs0, float* __restrict__ cs1, u16* __restrict__ xpad)
{
    const int stride = gridDim.x * blockDim.x;
    const int tid = blockIdx.x * blockDim.x + threadIdx.x;
    for (int i = tid; i < NG * HID; i += stride) {   // i8 packs (recurrent)
        int e = i & 15, l = (i >> 4) & 63, kc = (i >> 10) & 3, gt = i >> 12;
        int row = 16 * gt + (l & 15);
        int k = kc * 64 + (l >> 4) * 16 + e;
        float q0 = __builtin_rintf(Whh0[row * HID + k] * qs0[row]);
        float q1 = __builtin_rintf(Whh1[row * HID + k] * qs1[row]);
        wi80[i] = (i8)fminf(fmaxf(q0, -127.f), 127.f);
        wi81[i] = (i8)fminf(fmaxf(q1, -127.f), 127.f);
    }
    for (int i = tid; i < NG * HID; i += stride) {   // Wih1 bf16 frags, scaled
        int gt = i >> 12, kk = (i >> 9) & 7, l = (i >> 3) & 63, e = i & 7;
        wih1f[i] = f2bf(Wih1[(16 * gt + (l & 15)) * HID + kk * 32 + (l >> 4) * 8 + e] * LOG2E);
    }
    for (int i = tid; i < 32768; i += stride) {      // Wih0 bf16 frags, scaled
        int gt = i >> 9, l = (i >> 3) & 63, e = i & 7;
        int k = (l >> 4) * 8 + e;
        wih0f[i] = (k < 5) ? f2bf(Wih0[(16 * gt + (l & 15)) * 5 + k] * LOG2E) : (u16)0;
    }
    for (int i = tid; i < TSTEPS * BATCH * 8; i += stride) {  // x padded to 8, token-major
        int tok = i >> 3, k = i & 7, t = tok >> 8, b = tok & 255;
        xpad[i] = (k < 5) ? f2bf(x[((size_t)b * TSTEPS + t) * 5 + k]) : (u16)0;
    }
    for (int i = tid; i < BATCH * HID; i += stride) { hs0[i] = 0; hs1[i] = 0; cs0[i] = 0.f; cs1[i] = 0.f; }
}

// ---------------------------------------------------------------------------
// stage_fused(L): four pipeline roles on disjoint blocks (R8 structure):
//   blocks [0,64):    rec layer0, chunk L-1   (reads pre0, writes h0c)
//   blocks [64,128):  rec layer1, chunk L-3   (reads pre1)
//   blocks [128,160): gemm0: pre0(chunk L)   = log2e*(Wih0 x + b0)
//   blocks [160,224): gemm1: pre1(chunk L-2) = log2e*(Wih1 h0 + b1)
//
// R12 CHANGE (rec only): j-MAJOR step. Old kc-major MFMA order completed
// acc[0] at the 13th of 16 MFMAs -> all ~440 cyc/SIMD of cell VALU/trans
// exposed after the 1306-cyc MFMA issue stream. Now each gate's 4-MFMA
// chain completes early and its dequant+sigmoid/tanh issues on the VALU/
// trans pipes WHILE later gates' MFMAs occupy the matrix pipe. Per-acc kc
// order unchanged (0..3) and activation math unchanged -> bit-identical.
// pv prefetch hoisted above the MFMAs (same values, more latency slack).
// ---------------------------------------------------------------------------
__global__ __launch_bounds__(1024) __attribute__((amdgpu_waves_per_eu(4, 4)))
void stage_fused(int L,
    const u16* __restrict__ xpad8, const u16* __restrict__ wih0f, const float* __restrict__ b0s,
    const u16* __restrict__ wih1f, const float* __restrict__ b1s,
    u16* __restrict__ p0w, const u16* __restrict__ p0r,
    u16* __restrict__ h0w, const u16* __restrict__ h0r,
    u16* __restrict__ p1w, const u16* __restrict__ p1r,
    const i8* __restrict__ wi80, const i8* __restrict__ wi81,
    const float* __restrict__ dq0s, const float* __restrict__ dq1s,
    i8* __restrict__ hs0, i8* __restrict__ hs1,
    float* __restrict__ cs0, float* __restrict__ cs1)
{
    __shared__ __align__(16) char smem[16384];   // gemm1: 2x8KB A dbuf; rec: 2x1152B h_lds
    const int bid = blockIdx.x;
    const int tid = threadIdx.x, lane = tid & 63;
    const int col = lane & 15, kgrp = lane >> 4;

    if (bid < GB0) {
        // ---------------- recurrent role (BB=4, j-major step) ----------------
        const int layer = bid >> 6;
        if (layer == 0) { if (L < 1 || L > NCH) return; }
        else            { if (L < 3 || L > NCH + 2) return; }
        i8 (*h_lds)[BB * HSTR] = (i8 (*)[BB * HSTR])smem;
        const int btile = bid & 63;
        const u16* pre   = layer ? p1r : p0r;
        const i8*  wi8   = layer ? wi81 : wi80;
        const float* dq  = layer ? dq1s : dq0s;
        i8*    h_state   = layer ? hs1 : hs0;
        float* c_state   = layer ? cs1 : cs0;
        const int w = tid >> 6;
        const int b0 = btile * BB;
        const int u = w * 16 + col;          // h-unit this lane owns

        float sc[4];
        i32x4 wv[4][4];                      // 64 regs resident weights
#pragma unroll
        for (int j = 0; j < 4; j++) {
            const int gt = 16 * j + w;
            sc[j] = dq[gt * 16 + col];
#pragma unroll
            for (int kc = 0; kc < 4; kc++)
                wv[j][kc] = ((const i32x4*)wi8)[(gt * 4 + kc) * 64 + lane];
        }
        if (tid < 64 * BB) {
            const int rrow = tid >> 6, cc = (tid & 63) * 4;
            *(int*)&h_lds[0][rrow * HSTR + cc] = *(const int*)&h_state[(b0 + rrow) * HID + cc];
        }
        float c_reg = c_state[(size_t)(b0 + kgrp) * HID + u];

        // pre base for this lane: btile*4096 + u*4 + kgrp   (contiguous per wave)
        const u16* pb = pre + ((size_t)btile << 12) + (u << 2) + kgrp;
        u16 pvA[4], pvB[4];
#pragma unroll
        for (int j = 0; j < 4; j++) pvA[j] = pb[j << 10];
        // h0c store base in frag layout [t][kk=u>>5][bt=btile>>2][kgrpg=(u>>3)&3][colg][e=u&7]
        const size_t h0base = ((((size_t)(w >> 1) * 16 + (btile >> 2)) * 4
                               + ((w & 1) * 2 + (col >> 3))) * 16
                              + ((btile & 3) * 4 + kgrp)) * 8 + (col & 7);
        __syncthreads();

#define REC_STEP(T, CUR, PVC, PVN) do {                                             \
        _Pragma("unroll")                                                           \
        for (int j = 0; j < 4; j++)                                                 \
            asm volatile("" : "+v"(wv[j][0]), "+v"(wv[j][1]),                       \
                              "+v"(wv[j][2]), "+v"(wv[j][3]));                      \
        i32x4 a_[4];                                                                \
        _Pragma("unroll")                                                           \
        for (int kc = 0; kc < 4; kc++)                                              \
            a_[kc] = *(const i32x4*)&h_lds[CUR][(col >> 2) * HSTR + kc * 64 + kgrp * 16]; \
        const int tn_ = ((T) + 1 < CH) ? (T) + 1 : (T);                             \
        _Pragma("unroll")                                                           \
        for (int j = 0; j < 4; j++) PVN[j] = pb[(size_t)tn_ * PRE_TSTR + (j << 10)];\
        i32x4 acc0 = (i32x4){0, 0, 0, 0};                                           \
        _Pragma("unroll")                                                           \
        for (int kc = 0; kc < 4; kc++) acc0 = MFMA_I8(a_[kc], wv[0][kc], acc0);     \
        const float yi = fmaf((float)acc0[0], sc[0], bf2f(PVC[0]));                 \
        const float iv = sigm2(yi);                                                 \
        i32x4 acc1 = (i32x4){0, 0, 0, 0};                                           \
        _Pragma("unroll")                                                           \
        for (int kc = 0; kc < 4; kc++) acc1 = MFMA_I8(a_[kc], wv[1][kc], acc1);     \
        const float yf = fmaf((float)acc1[0], sc[1], bf2f(PVC[1]));                 \
        const float fv = sigm2(yf);                                                 \
        i32x4 acc2 = (i32x4){0, 0, 0, 0};                                           \
        _Pragma("unroll")                                                           \
        for (int kc = 0; kc < 4; kc++) acc2 = MFMA_I8(a_[kc], wv[2][kc], acc2);     \
        const float yg = fmaf((float)acc2[0], sc[2], bf2f(PVC[2]));                 \
        const float gv = tanh2(yg + yg);                                            \
        i32x4 acc3 = (i32x4){0, 0, 0, 0};                                           \
        _Pragma("unroll")                                                           \
        for (int kc = 0; kc < 4; kc++) acc3 = MFMA_I8(a_[kc], wv[3][kc], acc3);     \
        const float yo = fmaf((float)acc3[0], sc[3], bf2f(PVC[3]));                 \
        const float ov = sigm2(yo);                                                 \
        const float cn = fmaf(fv, c_reg, iv * gv);                                  \
        c_reg = cn;                                                                 \
        const float hv = ov * tanh2(cn * (2.f * LOG2E));                            \
        h_lds[(CUR) ^ 1][kgrp * HSTR + u] = (i8)__float2int_rn(hv * 127.f);         \
        if (layer == 0)                                                             \
            h0w[h0base + (size_t)(T) * H0C_TSTR] = f2bf(hv);                        \
        asm volatile("s_waitcnt lgkmcnt(0)" ::: "memory");                          \
        __builtin_amdgcn_s_barrier();                                               \
        __builtin_amdgcn_sched_barrier(0);                                          \
    } while (0)

#pragma unroll 1
        for (int t2 = 0; t2 < CH; t2 += 2) {
            REC_STEP(t2,     0, pvA, pvB);
            REC_STEP(t2 + 1, 1, pvB, pvA);
        }
#undef REC_STEP

        c_state[(size_t)(b0 + kgrp) * HID + u] = c_reg;
        if (tid < 64 * BB) {
            const int rrow = tid >> 6, cc = (tid & 63) * 4;
            *(int*)&h_state[(b0 + rrow) * HID + cc] = *(const int*)&h_lds[0][rrow * HSTR + cc];
        }
        return;
    } else if (bid < GB1) {
        // ---------------- gemm0: pre0(chunk L), 32 blocks x 1 tp x 16 bt ----------------
        if (L >= NCH) return;
        const int tp = bid - GB0;            // t' 0..31
        const int w = tid >> 6;              // wave 0..15
        const int j = w >> 2;                // pre j-chunk, constant per wave
        float bias[4];
        bf16x8 wv4[4];
#pragma unroll
        for (int tm = 0; tm < 4; tm++) {
            const int tile = w * 4 + tm;     // 16-gate tile 0..63
            bias[tm] = b0s[tile * 16 + col];
            wv4[tm] = *(const bf16x8*)&wih0f[((size_t)tile * 64 + lane) * 8];
        }
        const u16* Ab = xpad8 + ((size_t)L * CH + tp) * BATCH * 8;
#pragma unroll 1
        for (int btg = 0; btg < 16; btg++) {
            bf16x8 af = {0, 0, 0, 0, 0, 0, 0, 0};   // K beyond 8 is zero-padded
            if (kgrp == 0) af = *(const bf16x8*)&Ab[(btg * 16 + col) * 8];
            f32x4 acc[4];
#pragma unroll
            for (int tm = 0; tm < 4; tm++) acc[tm] = (f32x4){bias[tm], bias[tm], bias[tm], bias[tm]};
#pragma unroll
            for (int tm = 0; tm < 4; tm++) acc[tm] = MFMA_BF16(af, wv4[tm], acc[tm]);
            // batch = btg*16+kgrp*4+rr -> (btile = btg*4+kgrp, kb = rr): one 8B store.
#pragma unroll
            for (int tm = 0; tm < 4; tm++) {
                const int ul = ((w & 3) * 4 + tm) * 16 + col;   // u within j-chunk
                const size_t off = ((((size_t)tp * 64 + btg * 4 + kgrp) * 4 + j) << 10) + (ul << 2);
                u32x2 pk;
                pk.x = (unsigned)f2bf(acc[tm][0]) | ((unsigned)f2bf(acc[tm][1]) << 16);
                pk.y = (unsigned)f2bf(acc[tm][2]) | ((unsigned)f2bf(acc[tm][3]) << 16);
                *(u32x2*)&p0w[off] = pk;
            }
        }
        return;
    } else {
        // ---------------- gemm1: pre1(chunk L-2), 64 blocks x 2 tp, LDS-staged A ----------------
        if (L < 2 || L > NCH + 1) return;
        const int g = bid - GB1;             // 0..63
        const int j = g & 3;                 // j-chunk 0..3
        const int tpb = (g >> 2) * 2;        // t' base: 0,2,..,30
        const int w = tid >> 6;              // wave = 16-gate tile within j
        const int gt = j * 16 + w;           // global 16-gate tile
        const float bias = b1s[gt * 16 + col];
        bf16x8 wv8[8];                       // 32 regs resident weights
#pragma unroll
        for (int kk = 0; kk < 8; kk++)
            wv8[kk] = *(const bf16x8*)&wih1f[((size_t)(gt * 8 + kk) * 64 + lane) * 8];
        u16* As = (u16*)smem;                // [2][8][512] u16 double buffer
        const int kks = tid >> 7;            // staging slice: kk
        const int e4 = (tid & 127) * 4;      // 4 elements (8B) per thread
#pragma unroll 1
        for (int tpi = 0; tpi < 2; tpi++) {
            const int tp = tpb + tpi;
            const u16* Asrc = h0r + (size_t)tp * H0C_TSTR;
            {   // prologue: stage bt=0 into buf0
                u32x2 st = *(const u32x2*)&Asrc[((size_t)kks * 16 + 0) * 512 + e4];
                *(u32x2*)&As[kks * 512 + e4] = st;
            }
            __syncthreads();
#pragma unroll 1
            for (int bt = 0; bt < 16; bt++) {
                const int cur = bt & 1, nxt = cur ^ 1;
                u32x2 nx;
                if (bt + 1 < 16)   // issue next tile's global load early (hidden under MFMA)
                    nx = *(const u32x2*)&Asrc[((size_t)kks * 16 + bt + 1) * 512 + e4];
                bf16x8 a8[8];
#pragma unroll
                for (int kk = 0; kk < 8; kk++)
                    a8[kk] = *(const bf16x8*)&As[cur * 4096 + kk * 512 + lane * 8];
                f32x4 acc = (f32x4){bias, bias, bias, bias};
#pragma unroll
                for (int kk = 0; kk < 8; kk++)
                    acc = MFMA_BF16(a8[kk], wv8[kk], acc);
                const int ul = w * 16 + col;     // u within j-chunk
                const size_t off = ((((size_t)tp * 64 + bt * 4 + kgrp) * 4 + j) << 10) + (ul << 2);
                u32x2 pk;
                pk.x = (unsigned)f2bf(acc[0]) | ((unsigned)f2bf(acc[1]) << 16);
                pk.y = (unsigned)f2bf(acc[2]) | ((unsigned)f2bf(acc[3]) << 16);
                *(u32x2*)&p1w[off] = pk;
                if (bt + 1 < 16)
                    *(u32x2*)&As[nxt * 4096 + kks * 512 + e4] = nx;
                __syncthreads();                 // nxt fully written; cur reads done
            }
        }
        return;
    }
}

// ---------------------------------------------------------------------------
// head: y = sigmoid(relu(h_last) @ Wh^T + bh)
// ---------------------------------------------------------------------------
__global__ void head_kernel(const i8* __restrict__ hs1,
                            const float* __restrict__ Wh, const float* __restrict__ bh,
                            float* __restrict__ y) {
    int b = blockIdx.x;
    int l = threadIdx.x;
    const float inv127 = 1.f / 127.f;
    float hr[4];
#pragma unroll
    for (int i = 0; i < 4; ++i) hr[i] = fmaxf((float)hs1[b * HID + l + 64 * i] * inv127, 0.f);
    for (int o = 0; o < 3; ++o) {
        float s = 0.f;
#pragma unroll
        for (int i = 0; i < 4; ++i) s += hr[i] * Wh[o * HID + l + 64 * i];
        for (int off = 32; off > 0; off >>= 1) s += __shfl_down(s, off, 64);
        if (l == 0) y[b * 3 + o] = 1.f / (1.f + exp2_(-(s + bh[o]) * LOG2E));
    }
}

extern "C" void kernel_launch(void* const* d_in, const int* in_sizes, int n_in,
                              void* d_out, int out_size, void* d_ws, size_t ws_size,
                              hipStream_t stream) {
    const float* x    = (const float*)d_in[0];
    const float* Wih0 = (const float*)d_in[1];
    const float* Whh0 = (const float*)d_in[2];
    const float* bih0 = (const float*)d_in[3];
    const float* bhh0 = (const float*)d_in[4];
    const float* Wih1 = (const float*)d_in[5];
    const float* Whh1 = (const float*)d_in[6];
    const float* bih1 = (const float*)d_in[7];
    const float* bhh1 = (const float*)d_in[8];
    const float* Wh   = (const float*)d_in[9];
    const float* bh   = (const float*)d_in[10];

    char* ws = (char*)d_ws;
    i8*    wi80  = (i8*)(ws);                            // 256 KB
    i8*    wi81  = (i8*)(ws + ((size_t)256 << 10));      // 256 KB
    u16*   wih1f = (u16*)(ws + ((size_t)512 << 10));     // 512 KB
    u16*   wih0f = (u16*)(ws + ((size_t)1024 << 10));    // 64 KB
    float* qs0   = (float*)(ws + ((size_t)1088 << 10));
    float* dq0s  = (float*)(ws + ((size_t)1092 << 10));
    float* qs1   = (float*)(ws + ((size_t)1096 << 10));
    float* dq1s  = (float*)(ws + ((size_t)1100 << 10));
    float* b0s   = (float*)(ws + ((size_t)1104 << 10));
    float* b1s   = (float*)(ws + ((size_t)1108 << 10));
    i8*    hs0   = (i8*)(ws + ((size_t)1112 << 10));     // 64 KB
    i8*    hs1   = (i8*)(ws + ((size_t)1176 << 10));     // 64 KB
    float* cs0   = (float*)(ws + ((size_t)1240 << 10));  // 256 KB
    float* cs1   = (float*)(ws + ((size_t)1496 << 10));  // 256 KB
    u16*   xpad  = (u16*)(ws + ((size_t)1752 << 10));    // 2 MB  [tok][8] bf16
    u16*   h0c   = (u16*)(ws + ((size_t)4096 << 10));    // 2 x 4 MB (chunk parity)
    u16*   pre0  = (u16*)(ws + ((size_t)12288 << 10));   // 2 x 16 MB (chunk parity)
    u16*   pre1  = (u16*)(ws + ((size_t)45056 << 10));   // 2 x 16 MB -> total ~76 MB
    const size_t PRE_ELE = (size_t)CH * BATCH * NG;      // 8 Mi elements (16 MB)
    const size_t H0C_ELE = (size_t)CH * BATCH * HID;     // 2 Mi elements (4 MB)

    prep_a<<<16, 256, 0, stream>>>(Whh0, Whh1, bih0, bhh0, bih1, bhh1,
                                   qs0, dq0s, qs1, dq1s, b0s, b1s);
    prep_b<<<1024, 256, 0, stream>>>(x, Wih0, Whh0, Wih1, Whh1, qs0, qs1,
                                     wi80, wi81, wih1f, wih0f, hs0, hs1, cs0, cs1, xpad);
    // pipeline: gemm0(c=L) | rec0(c=L-1) | gemm1(c=L-2) | rec1(c=L-3)
    for (int L = 0; L <= NCH + 2; L++) {
        const size_t pA = (size_t)(L & 1), pB = pA ^ 1;
        stage_fused<<<NBLK, 1024, 0, stream>>>(L, xpad, wih0f, b0s, wih1f, b1s,
            pre0 + pA * PRE_ELE,        // gemm0 writes chunk L      (parity L)
            pre0 + pB * PRE_ELE,        // rec0 reads chunk L-1      (parity L-1)
            h0c  + pB * H0C_ELE,        // rec0 writes chunk L-1
            h0c  + pA * H0C_ELE,        // gemm1 reads chunk L-2     (parity L)
            pre1 + pA * PRE_ELE,        // gemm1 writes chunk L-2
            pre1 + pB * PRE_ELE,        // rec1 reads chunk L-3      (parity L-1)
            wi80, wi81, dq0s, dq1s, hs0, hs1, cs0, cs1);
    }
    head_kernel<<<BATCH, 64, 0, stream>>>(hs1, Wh, bh, (float*)d_out);
}